// Round 1
// 1409.458 us; speedup vs baseline: 1.2380x; 1.2380x over previous
//
#include <hip/hip_runtime.h>
#include <hip/hip_bf16.h>
#include <math.h>

#define DIM 512
#define VOCAB 10000
#define NPAD 10240
#define DEPTH 3
#define DSTATE 16
#define DCONV 4
#define DINNER 1024
#define DTRANK 32
#define BATCH 4
#define SEQ 1024
#define CTX 98
#define HEADS 8
#define DH 64
#define NTOK (BATCH*SEQ)   // 4096
#define NC 32              // scan chunks
#define LC 32              // chunk length

typedef __attribute__((ext_vector_type(8))) short short8;
typedef __attribute__((ext_vector_type(4))) float f32x4;

__device__ __forceinline__ float sigmoidf_(float x){ return 1.f/(1.f+__expf(-x)); }

__device__ __forceinline__ void gload_lds16(const void* g, void* s){
    __builtin_amdgcn_global_load_lds(
        (const __attribute__((address_space(1))) void*)g,
        (__attribute__((address_space(3))) void*)s, 16, 0, 0);
}

// ---------------------------------------------------------------- fp32 -> bf16 convert
__global__ __launch_bounds__(256)
void f2bf_kernel(const float* __restrict__ in, __hip_bfloat16* __restrict__ out)
{
    int i = (blockIdx.x*256 + threadIdx.x)*8;
    float4 a = *(const float4*)(in+i);
    float4 b = *(const float4*)(in+i+4);
    union { __hip_bfloat16 v[8]; short8 s; } o;
    o.v[0]=__float2bfloat16(a.x); o.v[1]=__float2bfloat16(a.y);
    o.v[2]=__float2bfloat16(a.z); o.v[3]=__float2bfloat16(a.w);
    o.v[4]=__float2bfloat16(b.x); o.v[5]=__float2bfloat16(b.y);
    o.v[6]=__float2bfloat16(b.z); o.v[7]=__float2bfloat16(b.w);
    *(short8*)(out+i) = o.s;
}

// ---------------------------------------------------------------- embedding
__global__ __launch_bounds__(128)
void embed_kernel(const int* __restrict__ x,
                  const float* __restrict__ tok_emb,
                  const float* __restrict__ pos_emb,
                  float* __restrict__ h)
{
    int row = blockIdx.x;
    int l = row & (SEQ-1);
    int tok = x[row];
    const float4* te = (const float4*)(tok_emb + (size_t)tok*DIM);
    const float4* pe = (const float4*)(pos_emb + (size_t)l*DIM);
    float4* hp = (float4*)(h + (size_t)row*DIM);
    int i = threadIdx.x;
    float4 a = te[i], b = pe[i];
    hp[i] = make_float4(a.x+b.x, a.y+b.y, a.z+b.z, a.w+b.w);
}

// ---------------------------------------------------------------- layernorm (bf16 out)
__global__ __launch_bounds__(256)
void layernorm_kernel(const float* __restrict__ in, const float* __restrict__ g,
                      const float* __restrict__ b, __hip_bfloat16* __restrict__ out)
{
    int row = blockIdx.x;
    const float* xr = in + (size_t)row*DIM;
    int t = threadIdx.x;
    float2 v = *(const float2*)(xr + t*2);
    float s  = v.x + v.y;
    float s2 = v.x*v.x + v.y*v.y;
    #pragma unroll
    for (int o=32;o>=1;o>>=1){ s += __shfl_xor(s,o); s2 += __shfl_xor(s2,o); }
    __shared__ float ss[4], ss2[4];
    int w = t>>6;
    if ((t&63)==0){ ss[w]=s; ss2[w]=s2; }
    __syncthreads();
    s  = ss[0]+ss[1]+ss[2]+ss[3];
    s2 = ss2[0]+ss2[1]+ss2[2]+ss2[3];
    float mu  = s * (1.f/DIM);
    float var = s2 * (1.f/DIM) - mu*mu;
    float rstd = rsqrtf(var + 1e-5f);
    float2 gg = *(const float2*)(g + t*2);
    float2 bb = *(const float2*)(b + t*2);
    __hip_bfloat162 o2;
    o2.x = __float2bfloat16((v.x-mu)*rstd*gg.x + bb.x);
    o2.y = __float2bfloat16((v.y-mu)*rstd*gg.y + bb.y);
    *(__hip_bfloat162*)(out + (size_t)row*DIM + t*2) = o2;
}

// ---------------------------------------------------------------- bf16 MFMA GEMM
// C[M,N] = A[M,K](bf16) @ W[N,K](bf16)^T (+bias) (+C). 128x128 tile, BK=32,
// 256 thr = 4 waves, each wave 64x64 via 4x4 grid of 16x16x32 MFMAs.
template<int BIAS, int RES, int NCHECK>
__global__ __launch_bounds__(256)
void gemm_bf16(const __hip_bfloat16* __restrict__ A, int lda,
               const __hip_bfloat16* __restrict__ W, int ldw,
               const float* __restrict__ bias,
               float* __restrict__ C, int ldc, int Nstore, int K)
{
    __shared__ __hip_bfloat16 As[128*32];
    __shared__ __hip_bfloat16 Ws[128*32];
    int t = threadIdx.x;
    int w = t >> 6, l = t & 63;
    int m0 = blockIdx.y*128, n0 = blockIdx.x*128;
    int wm = (w>>1)*64, wn = (w&1)*64;
    int lrow = l & 15, lq = l >> 4;
    f32x4 acc[4][4];
    #pragma unroll
    for (int i=0;i<4;i++)
        #pragma unroll
        for (int j=0;j<4;j++)
            acc[i][j] = (f32x4){0.f,0.f,0.f,0.f};

    for (int k0 = 0; k0 < K; k0 += 32){
        __syncthreads();
        #pragma unroll
        for (int it = 0; it < 2; ++it){
            int p = it*256 + t;            // 16B chunk index, 512 chunks/tile
            int r = p >> 2, c = (p & 3)*8;
            gload_lds16(A + (size_t)(m0+r)*lda + k0 + c, As + p*8);
            gload_lds16(W + (size_t)(n0+r)*ldw + k0 + c, Ws + p*8);
        }
        __syncthreads();
        short8 a[4], b[4];
        #pragma unroll
        for (int mt=0;mt<4;mt++)
            a[mt] = *(const short8*)(As + (wm + mt*16 + lrow)*32 + lq*8);
        #pragma unroll
        for (int nt=0;nt<4;nt++)
            b[nt] = *(const short8*)(Ws + (wn + nt*16 + lrow)*32 + lq*8);
        #pragma unroll
        for (int mt=0;mt<4;mt++)
            #pragma unroll
            for (int nt=0;nt<4;nt++)
                acc[mt][nt] = __builtin_amdgcn_mfma_f32_16x16x32_bf16(
                    a[mt], b[nt], acc[mt][nt], 0, 0, 0);
    }
    // epilogue: D row = wm+mt*16+lq*4+r, col = wn+nt*16+lrow
    #pragma unroll
    for (int nt=0;nt<4;nt++){
        int col = n0 + wn + nt*16 + lrow;
        if (NCHECK && col >= Nstore) continue;
        float bv = BIAS ? bias[col] : 0.f;
        #pragma unroll
        for (int mt=0;mt<4;mt++){
            #pragma unroll
            for (int r=0;r<4;r++){
                int row = m0 + wm + mt*16 + lq*4 + r;
                float v = acc[mt][nt][r] + bv;
                float* cp = C + (size_t)row*ldc + col;
                if (RES) v += *cp;
                *cp = v;
            }
        }
    }
}

// ---------------------------------------------------------------- generic fp32 GEMM (small/odd shapes)
template<int ACT, int BIAS, int RES>
__global__ __launch_bounds__(256)
void gemm_f32(const float* __restrict__ A, int lda,
              const float* __restrict__ W, int ldw,
              const float* __restrict__ bias,
              float* __restrict__ C, int ldc,
              int M, int N, int K)
{
    __shared__ float As[16][64];
    __shared__ float Ws[16][64];
    int t = threadIdx.x;
    int tx = t & 15, ty = t >> 4;
    int m0 = blockIdx.y * 64, n0 = blockIdx.x * 64;
    int loadRow = t >> 2;
    int loadK   = (t & 3) << 2;
    float acc[4][4] = {};
    for (int k0 = 0; k0 < K; k0 += 16) {
        {
            int gr = m0 + loadRow;
            float4 a4 = make_float4(0.f,0.f,0.f,0.f);
            if (gr < M) a4 = *(const float4*)(A + (size_t)gr*lda + k0 + loadK);
            As[loadK+0][loadRow] = a4.x;
            As[loadK+1][loadRow] = a4.y;
            As[loadK+2][loadRow] = a4.z;
            As[loadK+3][loadRow] = a4.w;
            int gn = n0 + loadRow;
            float4 w4 = make_float4(0.f,0.f,0.f,0.f);
            if (gn < N) w4 = *(const float4*)(W + (size_t)gn*ldw + k0 + loadK);
            Ws[loadK+0][loadRow] = w4.x;
            Ws[loadK+1][loadRow] = w4.y;
            Ws[loadK+2][loadRow] = w4.z;
            Ws[loadK+3][loadRow] = w4.w;
        }
        __syncthreads();
        #pragma unroll
        for (int k = 0; k < 16; ++k) {
            float4 a4 = *(const float4*)&As[k][ty<<2];
            float4 w4 = *(const float4*)&Ws[k][tx<<2];
            float a[4] = {a4.x,a4.y,a4.z,a4.w};
            float w[4] = {w4.x,w4.y,w4.z,w4.w};
            #pragma unroll
            for (int i=0;i<4;i++)
                #pragma unroll
                for (int j=0;j<4;j++)
                    acc[i][j] = fmaf(a[i], w[j], acc[i][j]);
        }
        __syncthreads();
    }
    #pragma unroll
    for (int i=0;i<4;i++){
        int row = m0 + (ty<<2) + i;
        if (row >= M) continue;
        #pragma unroll
        for (int j=0;j<4;j++){
            int col = n0 + (tx<<2) + j;
            if (col >= N) continue;
            float v = acc[i][j];
            if (BIAS) v += bias[col];
            if (ACT==1) v = (v > 20.f) ? v : log1pf(__expf(v));
            float* cp = C + (size_t)row*ldc + col;
            if (RES) v += *cp;
            *cp = v;
        }
    }
}

// ---------------------------------------------------------------- causal depthwise conv + SiLU
__global__ __launch_bounds__(256)
void conv_silu_kernel(const float* __restrict__ xz, const float* __restrict__ cw,
                      const float* __restrict__ cb, float* __restrict__ u)
{
    int idx = blockIdx.x*256 + threadIdx.x;
    int d = idx & (DINNER-1);
    int row = idx >> 10;
    int l = row & (SEQ-1);
    int bbase = row - l;
    float acc = cb[d];
    #pragma unroll
    for (int k=0;k<DCONV;k++){
        int ls = l - (DCONV-1) + k;
        if (ls >= 0)
            acc = fmaf(xz[((size_t)(bbase+ls))*(2*DINNER) + d], cw[d*DCONV+k], acc);
    }
    u[idx] = acc * sigmoidf_(acc);
}

// ---------------------------------------------------------------- chunked selective scan
__global__ __launch_bounds__(256)
void scan_pass1(const float* __restrict__ delta, const float* __restrict__ u,
                const float* __restrict__ xdbl, const float* __restrict__ A_log,
                float* __restrict__ hend, float* __restrict__ dsum_out)
{
    __shared__ float bc[LC][32];
    int c = blockIdx.x;
    int b = blockIdx.y >> 2, dg = blockIdx.y & 3;
    int t = threadIdx.x;
    int d = dg*256 + t;
    int rowbase = b*SEQ + c*LC;
    for (int idx = t; idx < LC*32; idx += 256){
        int r = idx >> 5, j = idx & 31;
        bc[r][j] = xdbl[(size_t)(rowbase + r)*64 + DTRANK + j];
    }
    float Av[DSTATE];
    #pragma unroll
    for (int s4 = 0; s4 < 4; ++s4){
        float4 a4 = *(const float4*)(A_log + (size_t)d*DSTATE + s4*4);
        Av[s4*4+0] = -__expf(a4.x);
        Av[s4*4+1] = -__expf(a4.y);
        Av[s4*4+2] = -__expf(a4.z);
        Av[s4*4+3] = -__expf(a4.w);
    }
    __syncthreads();
    float h[DSTATE] = {};
    float ds = 0.f;
    for (int tt = 0; tt < LC; ++tt){
        size_t row = (size_t)(rowbase + tt);
        float dlt = delta[row*DINNER + d];
        float uv  = u[row*DINNER + d];
        ds += dlt;
        float du = dlt*uv;
        #pragma unroll
        for (int s = 0; s < DSTATE; ++s)
            h[s] = fmaf(__expf(dlt*Av[s]), h[s], du*bc[tt][s]);
    }
    size_t base = ((size_t)(b*NC + c)*DINNER + d)*DSTATE;
    #pragma unroll
    for (int s4=0;s4<4;s4++)
        *(float4*)(hend + base + s4*4) =
            make_float4(h[s4*4],h[s4*4+1],h[s4*4+2],h[s4*4+3]);
    dsum_out[(size_t)(b*NC+c)*DINNER + d] = ds;
}

__global__ __launch_bounds__(256)
void scan_pass2(const float* __restrict__ hend, const float* __restrict__ dsum,
                const float* __restrict__ A_log, float* __restrict__ hin)
{
    int gid = blockIdx.x*256 + threadIdx.x;
    int s = gid & 15;
    int bd = gid >> 4;
    int d = bd & (DINNER-1);
    int b = bd >> 10;
    float Av = -__expf(A_log[(size_t)d*DSTATE + s]);
    float h = 0.f;
    for (int c = 0; c < NC; ++c){
        size_t idx = ((size_t)(b*NC + c)*DINNER + d)*DSTATE + s;
        hin[idx] = h;
        h = fmaf(__expf(Av*dsum[(size_t)(b*NC+c)*DINNER + d]), h, hend[idx]);
    }
}

// pass3: seeded local scan + y = sum_s h*C, + u*D, * silu(z)  -> bf16 y
__global__ __launch_bounds__(256)
void scan_pass3(const float* __restrict__ delta, const float* __restrict__ u,
                const float* __restrict__ xdbl, const float* __restrict__ xz,
                const float* __restrict__ A_log, const float* __restrict__ D_skip,
                const float* __restrict__ hin, __hip_bfloat16* __restrict__ y)
{
    __shared__ float bc[LC][32];
    int c = blockIdx.x;
    int b = blockIdx.y >> 2, dg = blockIdx.y & 3;
    int t = threadIdx.x;
    int d = dg*256 + t;
    int rowbase = b*SEQ + c*LC;
    for (int idx = t; idx < LC*32; idx += 256){
        int r = idx >> 5, j = idx & 31;
        bc[r][j] = xdbl[(size_t)(rowbase + r)*64 + DTRANK + j];
    }
    float Av[DSTATE];
    #pragma unroll
    for (int s4 = 0; s4 < 4; ++s4){
        float4 a4 = *(const float4*)(A_log + (size_t)d*DSTATE + s4*4);
        Av[s4*4+0] = -__expf(a4.x);
        Av[s4*4+1] = -__expf(a4.y);
        Av[s4*4+2] = -__expf(a4.z);
        Av[s4*4+3] = -__expf(a4.w);
    }
    float h[DSTATE];
    size_t hbase = ((size_t)(b*NC + c)*DINNER + d)*DSTATE;
    #pragma unroll
    for (int s4=0;s4<4;s4++){
        float4 h4 = *(const float4*)(hin + hbase + s4*4);
        h[s4*4+0]=h4.x; h[s4*4+1]=h4.y; h[s4*4+2]=h4.z; h[s4*4+3]=h4.w;
    }
    float Dv = D_skip[d];
    __syncthreads();
    for (int tt = 0; tt < LC; ++tt){
        size_t row = (size_t)(rowbase + tt);
        float dlt = delta[row*DINNER + d];
        float uv  = u[row*DINNER + d];
        float du = dlt*uv;
        float yv = 0.f;
        #pragma unroll
        for (int s = 0; s < DSTATE; ++s){
            h[s] = fmaf(__expf(dlt*Av[s]), h[s], du*bc[tt][s]);
            yv = fmaf(h[s], bc[tt][16+s], yv);
        }
        float zv = xz[row*(2*DINNER) + DINNER + d];
        y[row*DINNER + d] = __float2bfloat16((yv + uv*Dv) * (zv * sigmoidf_(zv)));
    }
}

// ---------------------------------------------------------------- MFMA cross-attention
// grid (B*HEADS, SEQ/128), 512 thr = 8 waves. Per block: one (b,h), 128 q-rows.
// LDS (all bf16, XOR-swizzled rows to kill ds_read_b128 bank conflicts):
//   Qs  [128][64]  q tile (A-operand layout [M][K])
//   Ks  [112][64]  k tile, rows 98..111 zero (B-operand layout [N][K])
//   Vt  [64][128]  V^T (B-operand [N=dh][K=s]), cols 98..127 zero
//   Pt  [128][128] softmax probs (A-operand [M][K]), cols 98..127 zero
#define QS_OFF 0           // 128 * 128B = 16384
#define KS_OFF 16384       // 112 * 128B = 14336
#define VT_OFF 30720       //  64 * 256B = 16384
#define PT_OFF 47104       // 128 * 256B = 32768
#define SMEM_BYTES 79872

__device__ __forceinline__ int swz(int row, int byteoff){
    return byteoff ^ ((row & 7) << 4);
}

__global__ __launch_bounds__(512)
void attn_mfma_kernel(const float* __restrict__ q, const float* __restrict__ k,
                      const float* __restrict__ v, __hip_bfloat16* __restrict__ outp,
                      float* __restrict__ Pg)
{
    __shared__ alignas(16) char smem[SMEM_BYTES];
    int t = threadIdx.x;
    int bh = blockIdx.x;
    int b = bh >> 3, h = bh & 7;
    int lrow0 = blockIdx.y * 128;               // row within batch
    size_t grow0 = (size_t)b*SEQ + lrow0;       // global token row

    // phase A: zero Vt + Pt (padding columns must be 0 for the PV K=128 MFMA)
    #pragma unroll
    for (int it = 0; it < 6; ++it)
        *(f32x4*)(smem + VT_OFF + (it*512 + t)*16) = (f32x4){0.f,0.f,0.f,0.f};
    __syncthreads();

    // phase B: stage Q, K, V^T as bf16 with row-XOR swizzle
    const float* qb = q + grow0*DIM + h*DH;
    #pragma unroll
    for (int it = 0; it < 4; ++it){
        int cidx = it*512 + t;                  // 2048 = 128 rows x 16 float4
        int row = cidx >> 4, c4 = cidx & 15;
        float4 a = *(const float4*)(qb + (size_t)row*DIM + c4*4);
        union { __hip_bfloat16 hh[4]; unsigned long long u; } pk;
        pk.hh[0]=__float2bfloat16(a.x); pk.hh[1]=__float2bfloat16(a.y);
        pk.hh[2]=__float2bfloat16(a.z); pk.hh[3]=__float2bfloat16(a.w);
        *(unsigned long long*)(smem + QS_OFF + row*128 + swz(row, c4*8)) = pk.u;
    }
    const float* kb = k + ((size_t)b*CTX)*DIM + h*DH;
    #pragma unroll
    for (int it = 0; it < 4; ++it){
        int cidx = it*512 + t;                  // need 1792 = 112 rows x 16
        if (cidx < 112*16){
            int row = cidx >> 4, c4 = cidx & 15;
            float4 a = make_float4(0.f,0.f,0.f,0.f);
            if (row < CTX) a = *(const float4*)(kb + (size_t)row*DIM + c4*4);
            union { __hip_bfloat16 hh[4]; unsigned long long u; } pk;
            pk.hh[0]=__float2bfloat16(a.x); pk.hh[1]=__float2bfloat16(a.y);
            pk.hh[2]=__float2bfloat16(a.z); pk.hh[3]=__float2bfloat16(a.w);
            *(unsigned long long*)(smem + KS_OFF + row*128 + swz(row, c4*8)) = pk.u;
        }
    }
    const float* vb = v + ((size_t)b*CTX)*DIM + h*DH;
    #pragma unroll
    for (int it = 0; it < 4; ++it){
        int c = it*512 + t;                     // need 1600 = 64 d x 25 s4
        if (c < 1600){
            int d = c & 63, s4 = c >> 6;
            union { __hip_bfloat16 hh[4]; unsigned long long u; } pk;
            #pragma unroll
            for (int j = 0; j < 4; ++j){
                int s = s4*4 + j;
                float vv = (s < CTX) ? vb[(size_t)s*DIM + d] : 0.f;
                pk.hh[j] = __float2bfloat16(vv);
            }
            *(unsigned long long*)(smem + VT_OFF + d*256 + swz(d, s4*8)) = pk.u;
        }
    }
    __syncthreads();

    // QK^T: wave w owns rows [w*16, w*16+16); cols 0..111 = 7 n-tiles; K=64
    int w = t >> 6, l = t & 63;
    int lr = l & 15, lq = l >> 4;
    f32x4 acc[7];
    #pragma unroll
    for (int nt = 0; nt < 7; ++nt) acc[nt] = (f32x4){0.f,0.f,0.f,0.f};
    #pragma unroll
    for (int kk = 0; kk < 2; ++kk){
        int arow = w*16 + lr;
        short8 af = *(const short8*)(smem + QS_OFF + arow*128 + swz(arow, kk*64 + lq*16));
        #pragma unroll
        for (int nt = 0; nt < 7; ++nt){
            int brow = nt*16 + lr;
            short8 bf = *(const short8*)(smem + KS_OFF + brow*128 + swz(brow, kk*64 + lq*16));
            acc[nt] = __builtin_amdgcn_mfma_f32_16x16x32_bf16(af, bf, acc[nt], 0, 0, 0);
        }
    }

    // softmax: row = w*16 + lq*4 + r, cols nt*16+lr spread over the 16 lanes
    // sharing lq (consecutive lanes) -> shfl_xor {1,2,4,8}. cols>=98 masked.
    float* Pgp = Pg + ((size_t)bh*SEQ + lrow0)*CTX;
    #pragma unroll
    for (int r = 0; r < 4; ++r){
        int row = w*16 + lq*4 + r;
        float vals[7];
        #pragma unroll
        for (int nt = 0; nt < 7; ++nt) vals[nt] = acc[nt][r] * 0.125f;
        if (lr >= 2) vals[6] = -1e30f;          // cols 98..111 invalid
        float m = vals[0];
        #pragma unroll
        for (int nt = 1; nt < 7; ++nt) m = fmaxf(m, vals[nt]);
        #pragma unroll
        for (int o = 8; o >= 1; o >>= 1) m = fmaxf(m, __shfl_xor(m, o));
        float ssum = 0.f;
        #pragma unroll
        for (int nt = 0; nt < 7; ++nt){ vals[nt] = __expf(vals[nt] - m); ssum += vals[nt]; }
        #pragma unroll
        for (int o = 8; o >= 1; o >>= 1) ssum += __shfl_xor(ssum, o);
        float inv = 1.f / ssum;
        #pragma unroll
        for (int nt = 0; nt < 7; ++nt){
            float p = vals[nt] * inv;
            int col = nt*16 + lr;
            *(__hip_bfloat16*)(smem + PT_OFF + row*256 + swz(row, col*2)) = __float2bfloat16(p);
            if (col < CTX) Pgp[(size_t)row*CTX + col] = p;   // fp32 probs for head-mean
        }
    }
    __syncthreads();

    // PV: out[rows w*16..+16][64] = Pt[rows][0..127] @ Vt; K=128 (4 k-steps)
    f32x4 acc2[4];
    #pragma unroll
    for (int nt = 0; nt < 4; ++nt) acc2[nt] = (f32x4){0.f,0.f,0.f,0.f};
    #pragma unroll
    for (int kk = 0; kk < 4; ++kk){
        int arow = w*16 + lr;
        short8 af = *(const short8*)(smem + PT_OFF + arow*256 + swz(arow, kk*64 + lq*16));
        #pragma unroll
        for (int nt = 0; nt < 4; ++nt){
            int brow = nt*16 + lr;
            short8 bf = *(const short8*)(smem + VT_OFF + brow*256 + swz(brow, kk*64 + lq*16));
            acc2[nt] = __builtin_amdgcn_mfma_f32_16x16x32_bf16(af, bf, acc2[nt], 0, 0, 0);
        }
    }
    #pragma unroll
    for (int nt = 0; nt < 4; ++nt){
        int col = h*DH + nt*16 + lr;
        #pragma unroll
        for (int r = 0; r < 4; ++r){
            int row = w*16 + lq*4 + r;
            outp[(grow0 + row)*DIM + col] = __float2bfloat16(acc2[nt][r]);
        }
    }
}

// mean over heads: attn_mean[b,l,s] = (1/8) sum_h Pg[b,h,l,s]
__global__ __launch_bounds__(256)
void attn_mean_kernel(const float* __restrict__ Pg, float* __restrict__ am)
{
    int idx = blockIdx.x*256 + threadIdx.x;     // NTOK*CTX = 401408 exact
    int row = idx / CTX;
    int s = idx - row*CTX;
    int b = row >> 10;
    int l = row & (SEQ-1);
    const float* p = Pg + ((size_t)(b*HEADS)*SEQ + l)*CTX + s;
    float acc = 0.f;
    #pragma unroll
    for (int h = 0; h < HEADS; ++h) acc += p[(size_t)h*SEQ*CTX];
    am[idx] = acc * 0.125f;
}

// ---------------------------------------------------------------- launcher
extern "C" void kernel_launch(void* const* d_in, const int* in_sizes, int n_in,
                              void* d_out, int out_size, void* d_ws, size_t ws_size,
                              hipStream_t stream)
{
    (void)in_sizes; (void)n_in; (void)out_size; (void)ws_size;
    const int*   x        = (const int*)  d_in[0];
    const float* context  = (const float*)d_in[1];
    const float* tok_emb  = (const float*)d_in[2];
    const float* pos_emb  = (const float*)d_in[3];
    const float* ln1_g    = (const float*)d_in[4];
    const float* ln1_b    = (const float*)d_in[5];
    const float* in_w     = (const float*)d_in[6];
    const float* conv_w   = (const float*)d_in[7];
    const float* conv_b   = (const float*)d_in[8];
    const float* xproj_w  = (const float*)d_in[9];
    const float* dt_w     = (const float*)d_in[10];
    const float* dt_b     = (const float*)d_in[11];
    const float* A_log    = (const float*)d_in[12];
    const float* D_skip   = (const float*)d_in[13];
    const float* out_w    = (const float*)d_in[14];
    const float* ln2_g    = (const float*)d_in[15];
    const float* ln2_b    = (const float*)d_in[16];
    const float* ain_w    = (const float*)d_in[17];
    const float* ain_b    = (const float*)d_in[18];
    const float* aout_w   = (const float*)d_in[19];
    const float* aout_b   = (const float*)d_in[20];
    const float* lnf_g    = (const float*)d_in[21];
    const float* lnf_b    = (const float*)d_in[22];
    const float* logit_w  = (const float*)d_in[23];
    const float* logit_b  = (const float*)d_in[24];
    float* out = (float*)d_out;

    // ---- workspace (fp32 + bf16 staging)
    float* ws = (float*)d_ws;
    size_t off = 0;
    float* hbuf  = ws + off;  off += (size_t)NTOK*DIM;        // 2.10M
    float* ubuf  = ws + off;  off += (size_t)NTOK*DINNER;     // 4.19M
    float* qbuf  = ws + off;  off += (size_t)NTOK*DIM;        // 2.10M
    float* xdbl  = ws + off;  off += (size_t)NTOK*64;         // 0.26M
    float* dbuf  = ws + off;  off += (size_t)NTOK*DINNER;     // 4.19M
    __hip_bfloat16* tnorm_bf   = (__hip_bfloat16*)(ws + off); off += (size_t)NTOK*DIM/2;
    __hip_bfloat16* logit_w_bf = (__hip_bfloat16*)(ws + off); off += (size_t)NPAD*DIM/2;
    float* kbuf = dbuf;                       // dead after scan
    float* vbuf = dbuf + 262144;
    float* Pgbuf = dbuf + 524288;             // 3.21M floats, fits in dbuf tail

    // ---- scratch in dead logits region of d_out (<19.8M of 40.96M floats)
    float* ob = out;
    float* xz    = ob;                 ob += (size_t)NTOK*2*DINNER;           // 8.39M
    float* hend  = ob;                 ob += (size_t)BATCH*NC*DINNER*DSTATE;  // 2.10M
    float* hinb  = ob;                 ob += (size_t)BATCH*NC*DINNER*DSTATE;  // 2.10M
    float* dsumb = ob;                 ob += (size_t)BATCH*NC*DINNER;         // 0.13M
    __hip_bfloat16* bfp = (__hip_bfloat16*)ob;
    __hip_bfloat16* in_w_bf   = bfp;   bfp += (size_t)DEPTH*2*DINNER*DIM;     // 3.15M
    __hip_bfloat16* out_w_bf  = bfp;   bfp += (size_t)DEPTH*DIM*DINNER;       // 1.57M
    __hip_bfloat16* ainw_bf   = bfp;   bfp += (size_t)DEPTH*3*DIM*DIM;        // 2.36M
    __hip_bfloat16* aoutw_bf  = bfp;   bfp += (size_t)DEPTH*DIM*DIM;          // 0.79M
    __hip_bfloat16* ybuf_bf   = bfp;   bfp += (size_t)NTOK*DINNER;            // 4.19M
    __hip_bfloat16* abuf_bf   = bfp;   bfp += (size_t)NTOK*DIM;               // 2.10M

    // ---- weight conversions (once per launch)
    f2bf_kernel<<<(DEPTH*2*DINNER*DIM)/2048, 256, 0, stream>>>(in_w, in_w_bf);
    f2bf_kernel<<<(DEPTH*DIM*DINNER)/2048, 256, 0, stream>>>(out_w, out_w_bf);
    f2bf_kernel<<<(DEPTH*3*DIM*DIM)/2048, 256, 0, stream>>>(ain_w, ainw_bf);
    f2bf_kernel<<<(DEPTH*DIM*DIM)/2048, 256, 0, stream>>>(aout_w, aoutw_bf);
    f2bf_kernel<<<(VOCAB*DIM)/2048, 256, 0, stream>>>(logit_w, logit_w_bf);
    hipMemsetAsync(logit_w_bf + (size_t)VOCAB*DIM, 0,
                   (size_t)(NPAD-VOCAB)*DIM*sizeof(__hip_bfloat16), stream);

    embed_kernel<<<NTOK, 128, 0, stream>>>(x, tok_emb, pos_emb, hbuf);

    float* attn_out_base = out + (size_t)NTOK*VOCAB;

    for (int i = 0; i < DEPTH; ++i){
        const float* Ai = A_log + (size_t)i*DINNER*DSTATE;
        layernorm_kernel<<<NTOK, 256, 0, stream>>>(hbuf, ln1_g + i*DIM, ln1_b + i*DIM, tnorm_bf);
        // in_proj: [4096,512]@[2048,512]^T -> xz
        gemm_bf16<0,0,0><<<dim3(2*DINNER/128, NTOK/128), 256, 0, stream>>>(
            tnorm_bf, DIM, in_w_bf + (size_t)i*2*DINNER*DIM, DIM, nullptr,
            xz, 2*DINNER, 2*DINNER, DIM);
        conv_silu_kernel<<<(NTOK*DINNER)/256, 256, 0, stream>>>(
            xz, conv_w + (size_t)i*DINNER*DCONV, conv_b + i*DINNER, ubuf);
        // x_proj (fp32, small N)
        gemm_f32<0,0,0><<<dim3(1, NTOK/64), 256, 0, stream>>>(
            ubuf, DINNER, xproj_w + (size_t)i*64*DINNER, DINNER, nullptr,
            xdbl, 64, NTOK, 64, DINNER);
        // dt_proj + softplus (fp32, K=32)
        gemm_f32<1,1,0><<<dim3(DINNER/64, NTOK/64), 256, 0, stream>>>(
            xdbl, 64, dt_w + (size_t)i*DINNER*DTRANK, DTRANK, dt_b + i*DINNER,
            dbuf, DINNER, NTOK, DINNER, DTRANK);
        // chunked selective scan -> ybuf_bf
        scan_pass1<<<dim3(NC, BATCH*4), 256, 0, stream>>>(
            dbuf, ubuf, xdbl, Ai, hend, dsumb);
        scan_pass2<<<(BATCH*DINNER*DSTATE)/256, 256, 0, stream>>>(
            hend, dsumb, Ai, hinb);
        scan_pass3<<<dim3(NC, BATCH*4), 256, 0, stream>>>(
            dbuf, ubuf, xdbl, xz, Ai, D_skip + i*DINNER, hinb, ybuf_bf);
        // out_proj + residual
        gemm_bf16<0,1,0><<<dim3(DIM/128, NTOK/128), 256, 0, stream>>>(
            ybuf_bf, DINNER, out_w_bf + (size_t)i*DIM*DINNER, DINNER, nullptr,
            hbuf, DIM, DIM, DINNER);
        layernorm_kernel<<<NTOK, 256, 0, stream>>>(hbuf, ln2_g + i*DIM, ln2_b + i*DIM, tnorm_bf);
        // q proj (bf16)
        gemm_bf16<1,0,0><<<dim3(DIM/128, NTOK/128), 256, 0, stream>>>(
            tnorm_bf, DIM, ainw_bf + (size_t)i*3*DIM*DIM, DIM, ain_b + (size_t)i*3*DIM,
            qbuf, DIM, DIM, DIM);
        // k/v proj (fp32, M=392)
        gemm_f32<0,1,0><<<dim3(DIM/64, (BATCH*CTX+63)/64), 256, 0, stream>>>(
            context, DIM, ain_w + (size_t)i*3*DIM*DIM + (size_t)DIM*DIM, DIM,
            ain_b + (size_t)i*3*DIM + DIM, kbuf, DIM, BATCH*CTX, DIM, DIM);
        gemm_f32<0,1,0><<<dim3(DIM/64, (BATCH*CTX+63)/64), 256, 0, stream>>>(
            context, DIM, ain_w + (size_t)i*3*DIM*DIM + (size_t)2*DIM*DIM, DIM,
            ain_b + (size_t)i*3*DIM + 2*DIM, vbuf, DIM, BATCH*CTX, DIM, DIM);
        // MFMA attention + head-mean
        attn_mfma_kernel<<<dim3(BATCH*HEADS, SEQ/128), 512, 0, stream>>>(
            qbuf, kbuf, vbuf, abuf_bf, Pgbuf);
        attn_mean_kernel<<<(NTOK*CTX)/256, 256, 0, stream>>>(
            Pgbuf, attn_out_base + (size_t)i*NTOK*CTX);
        // attn out proj + residual
        gemm_bf16<1,1,0><<<dim3(DIM/128, NTOK/128), 256, 0, stream>>>(
            abuf_bf, DIM, aoutw_bf + (size_t)i*DIM*DIM, DIM, aout_b + i*DIM,
            hbuf, DIM, DIM, DIM);
    }
    layernorm_kernel<<<NTOK, 256, 0, stream>>>(hbuf, lnf_g, lnf_b, tnorm_bf);
    // logits: N padded to 10240, store-masked to 10000
    gemm_bf16<1,0,1><<<dim3(NPAD/128, NTOK/128), 256, 0, stream>>>(
        tnorm_bf, DIM, logit_w_bf, DIM, logit_b, out, VOCAB, VOCAB, DIM);
}

// Round 2
// 1131.150 us; speedup vs baseline: 1.5426x; 1.2460x over previous
//
#include <hip/hip_runtime.h>
#include <hip/hip_bf16.h>
#include <math.h>

#define DIM 512
#define VOCAB 10000
#define NPAD 10240
#define DEPTH 3
#define DSTATE 16
#define DCONV 4
#define DINNER 1024
#define DTRANK 32
#define BATCH 4
#define SEQ 1024
#define CTX 98
#define HEADS 8
#define DH 64
#define NTOK (BATCH*SEQ)   // 4096
#define NC 32              // scan chunks
#define LC 32              // chunk length
#define KVLD 1024          // fused K|V row stride (bf16 elements)
#define CTXPAD 512         // context rows padded 392 -> 512

typedef __attribute__((ext_vector_type(8))) short short8;
typedef __attribute__((ext_vector_type(4))) float f32x4;

__device__ __forceinline__ float sigmoidf_(float x){ return 1.f/(1.f+__expf(-x)); }

__device__ __forceinline__ void gload_lds16(const void* g, void* s){
    __builtin_amdgcn_global_load_lds(
        (const __attribute__((address_space(1))) void*)g,
        (__attribute__((address_space(3))) void*)s, 16, 0, 0);
}

// ---------------------------------------------------------------- fp32 -> bf16 convert
__global__ __launch_bounds__(256)
void f2bf_kernel(const float* __restrict__ in, __hip_bfloat16* __restrict__ out)
{
    int i = (blockIdx.x*256 + threadIdx.x)*8;
    float4 a = *(const float4*)(in+i);
    float4 b = *(const float4*)(in+i+4);
    union { __hip_bfloat16 v[8]; short8 s; } o;
    o.v[0]=__float2bfloat16(a.x); o.v[1]=__float2bfloat16(a.y);
    o.v[2]=__float2bfloat16(a.z); o.v[3]=__float2bfloat16(a.w);
    o.v[4]=__float2bfloat16(b.x); o.v[5]=__float2bfloat16(b.y);
    o.v[6]=__float2bfloat16(b.z); o.v[7]=__float2bfloat16(b.w);
    *(short8*)(out+i) = o.s;
}

// ---------------------------------------------------------------- embedding
__global__ __launch_bounds__(128)
void embed_kernel(const int* __restrict__ x,
                  const float* __restrict__ tok_emb,
                  const float* __restrict__ pos_emb,
                  float* __restrict__ h)
{
    int row = blockIdx.x;
    int l = row & (SEQ-1);
    int tok = x[row];
    const float4* te = (const float4*)(tok_emb + (size_t)tok*DIM);
    const float4* pe = (const float4*)(pos_emb + (size_t)l*DIM);
    float4* hp = (float4*)(h + (size_t)row*DIM);
    int i = threadIdx.x;
    float4 a = te[i], b = pe[i];
    hp[i] = make_float4(a.x+b.x, a.y+b.y, a.z+b.z, a.w+b.w);
}

// ---------------------------------------------------------------- layernorm (bf16 out)
__global__ __launch_bounds__(256)
void layernorm_kernel(const float* __restrict__ in, const float* __restrict__ g,
                      const float* __restrict__ b, __hip_bfloat16* __restrict__ out)
{
    int row = blockIdx.x;
    const float* xr = in + (size_t)row*DIM;
    int t = threadIdx.x;
    float2 v = *(const float2*)(xr + t*2);
    float s  = v.x + v.y;
    float s2 = v.x*v.x + v.y*v.y;
    #pragma unroll
    for (int o=32;o>=1;o>>=1){ s += __shfl_xor(s,o); s2 += __shfl_xor(s2,o); }
    __shared__ float ss[4], ss2[4];
    int w = t>>6;
    if ((t&63)==0){ ss[w]=s; ss2[w]=s2; }
    __syncthreads();
    s  = ss[0]+ss[1]+ss[2]+ss[3];
    s2 = ss2[0]+ss2[1]+ss2[2]+ss2[3];
    float mu  = s * (1.f/DIM);
    float var = s2 * (1.f/DIM) - mu*mu;
    float rstd = rsqrtf(var + 1e-5f);
    float2 gg = *(const float2*)(g + t*2);
    float2 bb = *(const float2*)(b + t*2);
    __hip_bfloat162 o2;
    o2.x = __float2bfloat16((v.x-mu)*rstd*gg.x + bb.x);
    o2.y = __float2bfloat16((v.y-mu)*rstd*gg.y + bb.y);
    *(__hip_bfloat162*)(out + (size_t)row*DIM + t*2) = o2;
}

// ---------------------------------------------------------------- bf16 MFMA GEMM
// C[M,N] = A[M,K](bf16) @ W[N,K](bf16)^T (+bias) (+C). 128x128 tile, BK=32,
// 256 thr = 4 waves, each wave 64x64 via 4x4 grid of 16x16x32 MFMAs.
// OUTBF: store bf16 (no residual support in that mode).
template<int BIAS, int RES, int NCHECK, int OUTBF>
__global__ __launch_bounds__(256)
void gemm_bf16(const __hip_bfloat16* __restrict__ A, int lda,
               const __hip_bfloat16* __restrict__ W, int ldw,
               const float* __restrict__ bias,
               void* __restrict__ Cv, int ldc, int Nstore, int K)
{
    __shared__ __hip_bfloat16 As[128*32];
    __shared__ __hip_bfloat16 Ws[128*32];
    int t = threadIdx.x;
    int w = t >> 6, l = t & 63;
    int m0 = blockIdx.y*128, n0 = blockIdx.x*128;
    int wm = (w>>1)*64, wn = (w&1)*64;
    int lrow = l & 15, lq = l >> 4;
    f32x4 acc[4][4];
    #pragma unroll
    for (int i=0;i<4;i++)
        #pragma unroll
        for (int j=0;j<4;j++)
            acc[i][j] = (f32x4){0.f,0.f,0.f,0.f};

    for (int k0 = 0; k0 < K; k0 += 32){
        __syncthreads();
        #pragma unroll
        for (int it = 0; it < 2; ++it){
            int p = it*256 + t;            // 16B chunk index, 512 chunks/tile
            int r = p >> 2, c = (p & 3)*8;
            gload_lds16(A + (size_t)(m0+r)*lda + k0 + c, As + p*8);
            gload_lds16(W + (size_t)(n0+r)*ldw + k0 + c, Ws + p*8);
        }
        __syncthreads();
        short8 a[4], b[4];
        #pragma unroll
        for (int mt=0;mt<4;mt++)
            a[mt] = *(const short8*)(As + (wm + mt*16 + lrow)*32 + lq*8);
        #pragma unroll
        for (int nt=0;nt<4;nt++)
            b[nt] = *(const short8*)(Ws + (wn + nt*16 + lrow)*32 + lq*8);
        #pragma unroll
        for (int mt=0;mt<4;mt++)
            #pragma unroll
            for (int nt=0;nt<4;nt++)
                acc[mt][nt] = __builtin_amdgcn_mfma_f32_16x16x32_bf16(
                    a[mt], b[nt], acc[mt][nt], 0, 0, 0);
    }
    // epilogue: D row = wm+mt*16+lq*4+r, col = wn+nt*16+lrow
    #pragma unroll
    for (int nt=0;nt<4;nt++){
        int col = n0 + wn + nt*16 + lrow;
        if (NCHECK && col >= Nstore) continue;
        float bv = BIAS ? bias[col] : 0.f;
        #pragma unroll
        for (int mt=0;mt<4;mt++){
            #pragma unroll
            for (int r=0;r<4;r++){
                int row = m0 + wm + mt*16 + lq*4 + r;
                float v = acc[mt][nt][r] + bv;
                if (OUTBF){
                    __hip_bfloat16* cp = (__hip_bfloat16*)Cv + (size_t)row*ldc + col;
                    *cp = __float2bfloat16(v);
                } else {
                    float* cp = (float*)Cv + (size_t)row*ldc + col;
                    if (RES) v += *cp;
                    *cp = v;
                }
            }
        }
    }
}

// ---------------------------------------------------------------- generic fp32 GEMM (small/odd shapes)
template<int ACT, int BIAS, int RES>
__global__ __launch_bounds__(256)
void gemm_f32(const float* __restrict__ A, int lda,
              const float* __restrict__ W, int ldw,
              const float* __restrict__ bias,
              float* __restrict__ C, int ldc,
              int M, int N, int K)
{
    __shared__ float As[16][64];
    __shared__ float Ws[16][64];
    int t = threadIdx.x;
    int tx = t & 15, ty = t >> 4;
    int m0 = blockIdx.y * 64, n0 = blockIdx.x * 64;
    int loadRow = t >> 2;
    int loadK   = (t & 3) << 2;
    float acc[4][4] = {};
    for (int k0 = 0; k0 < K; k0 += 16) {
        {
            int gr = m0 + loadRow;
            float4 a4 = make_float4(0.f,0.f,0.f,0.f);
            if (gr < M) a4 = *(const float4*)(A + (size_t)gr*lda + k0 + loadK);
            As[loadK+0][loadRow] = a4.x;
            As[loadK+1][loadRow] = a4.y;
            As[loadK+2][loadRow] = a4.z;
            As[loadK+3][loadRow] = a4.w;
            int gn = n0 + loadRow;
            float4 w4 = make_float4(0.f,0.f,0.f,0.f);
            if (gn < N) w4 = *(const float4*)(W + (size_t)gn*ldw + k0 + loadK);
            Ws[loadK+0][loadRow] = w4.x;
            Ws[loadK+1][loadRow] = w4.y;
            Ws[loadK+2][loadRow] = w4.z;
            Ws[loadK+3][loadRow] = w4.w;
        }
        __syncthreads();
        #pragma unroll
        for (int k = 0; k < 16; ++k) {
            float4 a4 = *(const float4*)&As[k][ty<<2];
            float4 w4 = *(const float4*)&Ws[k][tx<<2];
            float a[4] = {a4.x,a4.y,a4.z,a4.w};
            float w[4] = {w4.x,w4.y,w4.z,w4.w};
            #pragma unroll
            for (int i=0;i<4;i++)
                #pragma unroll
                for (int j=0;j<4;j++)
                    acc[i][j] = fmaf(a[i], w[j], acc[i][j]);
        }
        __syncthreads();
    }
    #pragma unroll
    for (int i=0;i<4;i++){
        int row = m0 + (ty<<2) + i;
        if (row >= M) continue;
        #pragma unroll
        for (int j=0;j<4;j++){
            int col = n0 + (tx<<2) + j;
            if (col >= N) continue;
            float v = acc[i][j];
            if (BIAS) v += bias[col];
            if (ACT==1) v = (v > 20.f) ? v : log1pf(__expf(v));
            float* cp = C + (size_t)row*ldc + col;
            if (RES) v += *cp;
            *cp = v;
        }
    }
}

// ---------------------------------------------------------------- causal depthwise conv + SiLU (fp32 + bf16 out)
__global__ __launch_bounds__(256)
void conv_silu_kernel(const float* __restrict__ xz, const float* __restrict__ cw,
                      const float* __restrict__ cb, float* __restrict__ u,
                      __hip_bfloat16* __restrict__ ubf)
{
    int idx = blockIdx.x*256 + threadIdx.x;
    int d = idx & (DINNER-1);
    int row = idx >> 10;
    int l = row & (SEQ-1);
    int bbase = row - l;
    float acc = cb[d];
    #pragma unroll
    for (int k=0;k<DCONV;k++){
        int ls = l - (DCONV-1) + k;
        if (ls >= 0)
            acc = fmaf(xz[((size_t)(bbase+ls))*(2*DINNER) + d], cw[d*DCONV+k], acc);
    }
    float uv = acc * sigmoidf_(acc);
    u[idx] = uv;
    ubf[idx] = __float2bfloat16(uv);
}

// ---------------------------------------------------------------- chunked selective scan
__global__ __launch_bounds__(256)
void scan_pass1(const float* __restrict__ delta, const float* __restrict__ u,
                const float* __restrict__ xdbl, const float* __restrict__ A_log,
                float* __restrict__ hend, float* __restrict__ dsum_out)
{
    __shared__ float bc[LC][32];
    int c = blockIdx.x;
    int b = blockIdx.y >> 2, dg = blockIdx.y & 3;
    int t = threadIdx.x;
    int d = dg*256 + t;
    int rowbase = b*SEQ + c*LC;
    for (int idx = t; idx < LC*32; idx += 256){
        int r = idx >> 5, j = idx & 31;
        bc[r][j] = xdbl[(size_t)(rowbase + r)*64 + DTRANK + j];
    }
    float Av[DSTATE];
    #pragma unroll
    for (int s4 = 0; s4 < 4; ++s4){
        float4 a4 = *(const float4*)(A_log + (size_t)d*DSTATE + s4*4);
        Av[s4*4+0] = -__expf(a4.x);
        Av[s4*4+1] = -__expf(a4.y);
        Av[s4*4+2] = -__expf(a4.z);
        Av[s4*4+3] = -__expf(a4.w);
    }
    __syncthreads();
    float h[DSTATE] = {};
    float ds = 0.f;
    for (int tt = 0; tt < LC; ++tt){
        size_t row = (size_t)(rowbase + tt);
        float dlt = delta[row*DINNER + d];
        float uv  = u[row*DINNER + d];
        ds += dlt;
        float du = dlt*uv;
        #pragma unroll
        for (int s = 0; s < DSTATE; ++s)
            h[s] = fmaf(__expf(dlt*Av[s]), h[s], du*bc[tt][s]);
    }
    size_t base = ((size_t)(b*NC + c)*DINNER + d)*DSTATE;
    #pragma unroll
    for (int s4=0;s4<4;s4++)
        *(float4*)(hend + base + s4*4) =
            make_float4(h[s4*4],h[s4*4+1],h[s4*4+2],h[s4*4+3]);
    dsum_out[(size_t)(b*NC+c)*DINNER + d] = ds;
}

__global__ __launch_bounds__(256)
void scan_pass2(const float* __restrict__ hend, const float* __restrict__ dsum,
                const float* __restrict__ A_log, float* __restrict__ hin)
{
    int gid = blockIdx.x*256 + threadIdx.x;
    int s = gid & 15;
    int bd = gid >> 4;
    int d = bd & (DINNER-1);
    int b = bd >> 10;
    float Av = -__expf(A_log[(size_t)d*DSTATE + s]);
    float h = 0.f;
    for (int c = 0; c < NC; ++c){
        size_t idx = ((size_t)(b*NC + c)*DINNER + d)*DSTATE + s;
        hin[idx] = h;
        h = fmaf(__expf(Av*dsum[(size_t)(b*NC+c)*DINNER + d]), h, hend[idx]);
    }
}

// pass3: seeded local scan + y = sum_s h*C, + u*D, * silu(z)  -> bf16 y
__global__ __launch_bounds__(256)
void scan_pass3(const float* __restrict__ delta, const float* __restrict__ u,
                const float* __restrict__ xdbl, const float* __restrict__ xz,
                const float* __restrict__ A_log, const float* __restrict__ D_skip,
                const float* __restrict__ hin, __hip_bfloat16* __restrict__ y)
{
    __shared__ float bc[LC][32];
    int c = blockIdx.x;
    int b = blockIdx.y >> 2, dg = blockIdx.y & 3;
    int t = threadIdx.x;
    int d = dg*256 + t;
    int rowbase = b*SEQ + c*LC;
    for (int idx = t; idx < LC*32; idx += 256){
        int r = idx >> 5, j = idx & 31;
        bc[r][j] = xdbl[(size_t)(rowbase + r)*64 + DTRANK + j];
    }
    float Av[DSTATE];
    #pragma unroll
    for (int s4 = 0; s4 < 4; ++s4){
        float4 a4 = *(const float4*)(A_log + (size_t)d*DSTATE + s4*4);
        Av[s4*4+0] = -__expf(a4.x);
        Av[s4*4+1] = -__expf(a4.y);
        Av[s4*4+2] = -__expf(a4.z);
        Av[s4*4+3] = -__expf(a4.w);
    }
    float h[DSTATE];
    size_t hbase = ((size_t)(b*NC + c)*DINNER + d)*DSTATE;
    #pragma unroll
    for (int s4=0;s4<4;s4++){
        float4 h4 = *(const float4*)(hin + hbase + s4*4);
        h[s4*4+0]=h4.x; h[s4*4+1]=h4.y; h[s4*4+2]=h4.z; h[s4*4+3]=h4.w;
    }
    float Dv = D_skip[d];
    __syncthreads();
    for (int tt = 0; tt < LC; ++tt){
        size_t row = (size_t)(rowbase + tt);
        float dlt = delta[row*DINNER + d];
        float uv  = u[row*DINNER + d];
        float du = dlt*uv;
        float yv = 0.f;
        #pragma unroll
        for (int s = 0; s < DSTATE; ++s){
            h[s] = fmaf(__expf(dlt*Av[s]), h[s], du*bc[tt][s]);
            yv = fmaf(h[s], bc[tt][16+s], yv);
        }
        float zv = xz[row*(2*DINNER) + DINNER + d];
        y[row*DINNER + d] = __float2bfloat16((yv + uv*Dv) * (zv * sigmoidf_(zv)));
    }
}

// ---------------------------------------------------------------- MFMA cross-attention
// grid (B*HEADS, SEQ/128), 512 thr = 8 waves. Per block: one (b,h), 128 q-rows.
// Inputs already bf16: q [NTOK][512], kv [CTXPAD][1024] (K = cols 0..511, V = 512..1023).
// LDS (all bf16, XOR-swizzled rows to kill ds_read_b128 bank conflicts):
//   Qs  [128][64]  q tile (A-operand layout [M][K])
//   Ks  [112][64]  k tile, rows 98..111 zero (B-operand layout [N][K])
//   Vt  [64][128]  V^T (B-operand [N=dh][K=s]), cols 98..127 zero
//   Pt  [128][128] softmax probs (A-operand [M][K]), cols 98..127 zero
#define QS_OFF 0           // 128 * 128B = 16384
#define KS_OFF 16384       // 112 * 128B = 14336
#define VT_OFF 30720       //  64 * 256B = 16384
#define PT_OFF 47104       // 128 * 256B = 32768
#define SMEM_BYTES 79872

__device__ __forceinline__ int swz(int row, int byteoff){
    return byteoff ^ ((row & 7) << 4);
}

__global__ __launch_bounds__(512)
void attn_mfma_kernel(const __hip_bfloat16* __restrict__ q,
                      const __hip_bfloat16* __restrict__ kv,
                      __hip_bfloat16* __restrict__ outp,
                      float* __restrict__ Pg)
{
    __shared__ alignas(16) char smem[SMEM_BYTES];
    int t = threadIdx.x;
    int bh = blockIdx.x;
    int b = bh >> 3, h = bh & 7;
    int lrow0 = blockIdx.y * 128;               // row within batch
    size_t grow0 = (size_t)b*SEQ + lrow0;       // global token row

    // phase A: zero Vt + Pt (padding columns must be 0 for the PV K=128 MFMA)
    #pragma unroll
    for (int it = 0; it < 6; ++it)
        *(f32x4*)(smem + VT_OFF + (it*512 + t)*16) = (f32x4){0.f,0.f,0.f,0.f};
    __syncthreads();

    // phase B: stage Q, K, V^T (bf16 copies, row-XOR swizzle)
    const __hip_bfloat16* qb = q + grow0*DIM + h*DH;
    #pragma unroll
    for (int it = 0; it < 2; ++it){
        int cidx = it*512 + t;                  // 1024 = 128 rows x 8 chunks(16B)
        int row = cidx >> 3, c8 = cidx & 7;
        short8 a = *(const short8*)(qb + (size_t)row*DIM + c8*8);
        *(short8*)(smem + QS_OFF + row*128 + swz(row, c8*16)) = a;
    }
    const __hip_bfloat16* kb = kv + (size_t)(b*CTX)*KVLD + h*DH;
    #pragma unroll
    for (int it = 0; it < 2; ++it){
        int cidx = it*512 + t;                  // need 896 = 112 rows x 8
        if (cidx < 112*8){
            int row = cidx >> 3, c8 = cidx & 7;
            short8 a = (short8){0,0,0,0,0,0,0,0};
            if (row < CTX) a = *(const short8*)(kb + (size_t)row*KVLD + c8*8);
            *(short8*)(smem + KS_OFF + row*128 + swz(row, c8*16)) = a;
        }
    }
    const __hip_bfloat16* vb = kv + (size_t)(b*CTX)*KVLD + DIM + h*DH;
    #pragma unroll
    for (int it = 0; it < 4; ++it){
        int c = it*512 + t;                     // need 1600 = 64 d x 25 s4
        if (c < 1600){
            int d = c & 63, s4 = c >> 6;
            union { unsigned short hh[4]; unsigned long long u; } pk;
            #pragma unroll
            for (int j = 0; j < 4; ++j){
                int s = s4*4 + j;
                pk.hh[j] = (s < CTX) ? *(const unsigned short*)(vb + (size_t)s*KVLD + d) : 0;
            }
            *(unsigned long long*)(smem + VT_OFF + d*256 + swz(d, s4*8)) = pk.u;
        }
    }
    __syncthreads();

    // QK^T: wave w owns rows [w*16, w*16+16); cols 0..111 = 7 n-tiles; K=64
    int w = t >> 6, l = t & 63;
    int lr = l & 15, lq = l >> 4;
    f32x4 acc[7];
    #pragma unroll
    for (int nt = 0; nt < 7; ++nt) acc[nt] = (f32x4){0.f,0.f,0.f,0.f};
    #pragma unroll
    for (int kk = 0; kk < 2; ++kk){
        int arow = w*16 + lr;
        short8 af = *(const short8*)(smem + QS_OFF + arow*128 + swz(arow, kk*64 + lq*16));
        #pragma unroll
        for (int nt = 0; nt < 7; ++nt){
            int brow = nt*16 + lr;
            short8 bf = *(const short8*)(smem + KS_OFF + brow*128 + swz(brow, kk*64 + lq*16));
            acc[nt] = __builtin_amdgcn_mfma_f32_16x16x32_bf16(af, bf, acc[nt], 0, 0, 0);
        }
    }

    // softmax: row = w*16 + lq*4 + r, cols nt*16+lr spread over the 16 lanes
    // sharing lq (consecutive lanes) -> shfl_xor {1,2,4,8}. cols>=98 masked.
    float* Pgp = Pg + ((size_t)bh*SEQ + lrow0)*CTX;
    #pragma unroll
    for (int r = 0; r < 4; ++r){
        int row = w*16 + lq*4 + r;
        float vals[7];
        #pragma unroll
        for (int nt = 0; nt < 7; ++nt) vals[nt] = acc[nt][r] * 0.125f;
        if (lr >= 2) vals[6] = -1e30f;          // cols 98..111 invalid
        float m = vals[0];
        #pragma unroll
        for (int nt = 1; nt < 7; ++nt) m = fmaxf(m, vals[nt]);
        #pragma unroll
        for (int o = 8; o >= 1; o >>= 1) m = fmaxf(m, __shfl_xor(m, o));
        float ssum = 0.f;
        #pragma unroll
        for (int nt = 0; nt < 7; ++nt){ vals[nt] = __expf(vals[nt] - m); ssum += vals[nt]; }
        #pragma unroll
        for (int o = 8; o >= 1; o >>= 1) ssum += __shfl_xor(ssum, o);
        float inv = 1.f / ssum;
        #pragma unroll
        for (int nt = 0; nt < 7; ++nt){
            float p = vals[nt] * inv;
            int col = nt*16 + lr;
            *(__hip_bfloat16*)(smem + PT_OFF + row*256 + swz(row, col*2)) = __float2bfloat16(p);
            if (col < CTX) Pgp[(size_t)row*CTX + col] = p;   // fp32 probs for head-mean
        }
    }
    __syncthreads();

    // PV: out[rows w*16..+16][64] = Pt[rows][0..127] @ Vt; K=128 (4 k-steps)
    f32x4 acc2[4];
    #pragma unroll
    for (int nt = 0; nt < 4; ++nt) acc2[nt] = (f32x4){0.f,0.f,0.f,0.f};
    #pragma unroll
    for (int kk = 0; kk < 4; ++kk){
        int arow = w*16 + lr;
        short8 af = *(const short8*)(smem + PT_OFF + arow*256 + swz(arow, kk*64 + lq*16));
        #pragma unroll
        for (int nt = 0; nt < 4; ++nt){
            int brow = nt*16 + lr;
            short8 bf = *(const short8*)(smem + VT_OFF + brow*256 + swz(brow, kk*64 + lq*16));
            acc2[nt] = __builtin_amdgcn_mfma_f32_16x16x32_bf16(af, bf, acc2[nt], 0, 0, 0);
        }
    }
    #pragma unroll
    for (int nt = 0; nt < 4; ++nt){
        int col = h*DH + nt*16 + lr;
        #pragma unroll
        for (int r = 0; r < 4; ++r){
            int row = w*16 + lq*4 + r;
            outp[(grow0 + row)*DIM + col] = __float2bfloat16(acc2[nt][r]);
        }
    }
}

// mean over heads: attn_mean[b,l,s] = (1/8) sum_h Pg[b,h,l,s]
__global__ __launch_bounds__(256)
void attn_mean_kernel(const float* __restrict__ Pg, float* __restrict__ am)
{
    int idx = blockIdx.x*256 + threadIdx.x;     // NTOK*CTX = 401408 exact
    int row = idx / CTX;
    int s = idx - row*CTX;
    int b = row >> 10;
    int l = row & (SEQ-1);
    const float* p = Pg + ((size_t)(b*HEADS)*SEQ + l)*CTX + s;
    float acc = 0.f;
    #pragma unroll
    for (int h = 0; h < HEADS; ++h) acc += p[(size_t)h*SEQ*CTX];
    am[idx] = acc * 0.125f;
}

// ---------------------------------------------------------------- launcher
extern "C" void kernel_launch(void* const* d_in, const int* in_sizes, int n_in,
                              void* d_out, int out_size, void* d_ws, size_t ws_size,
                              hipStream_t stream)
{
    (void)in_sizes; (void)n_in; (void)out_size; (void)ws_size;
    const int*   x        = (const int*)  d_in[0];
    const float* context  = (const float*)d_in[1];
    const float* tok_emb  = (const float*)d_in[2];
    const float* pos_emb  = (const float*)d_in[3];
    const float* ln1_g    = (const float*)d_in[4];
    const float* ln1_b    = (const float*)d_in[5];
    const float* in_w     = (const float*)d_in[6];
    const float* conv_w   = (const float*)d_in[7];
    const float* conv_b   = (const float*)d_in[8];
    const float* xproj_w  = (const float*)d_in[9];
    const float* dt_w     = (const float*)d_in[10];
    const float* dt_b     = (const float*)d_in[11];
    const float* A_log    = (const float*)d_in[12];
    const float* D_skip   = (const float*)d_in[13];
    const float* out_w    = (const float*)d_in[14];
    const float* ln2_g    = (const float*)d_in[15];
    const float* ln2_b    = (const float*)d_in[16];
    const float* ain_w    = (const float*)d_in[17];
    const float* ain_b    = (const float*)d_in[18];
    const float* aout_w   = (const float*)d_in[19];
    const float* aout_b   = (const float*)d_in[20];
    const float* lnf_g    = (const float*)d_in[21];
    const float* lnf_b    = (const float*)d_in[22];
    const float* logit_w  = (const float*)d_in[23];
    const float* logit_b  = (const float*)d_in[24];
    float* out = (float*)d_out;

    // ---- workspace (fp32 + bf16 staging)
    float* ws = (float*)d_ws;
    size_t off = 0;
    float* hbuf  = ws + off;  off += (size_t)NTOK*DIM;        // 2.10M
    float* ubuf  = ws + off;  off += (size_t)NTOK*DINNER;     // 4.19M
    float* xdbl  = ws + off;  off += (size_t)NTOK*64;         // 0.26M
    float* dbuf  = ws + off;  off += (size_t)NTOK*DINNER;     // 4.19M
    __hip_bfloat16* tnorm_bf   = (__hip_bfloat16*)(ws + off); off += (size_t)NTOK*DIM/2;
    __hip_bfloat16* logit_w_bf = (__hip_bfloat16*)(ws + off); off += (size_t)NPAD*DIM/2;
    float* Pgbuf = dbuf;                      // dead after scan; 3.21M < 4.19M floats

    // ---- scratch in dead logits region of d_out (first 40.96M floats)
    float* ob = out;
    float* xz    = ob;                 ob += (size_t)NTOK*2*DINNER;           // 8.39M
    float* hend  = ob;                 ob += (size_t)BATCH*NC*DINNER*DSTATE;  // 2.10M
    float* hinb  = ob;                 ob += (size_t)BATCH*NC*DINNER*DSTATE;  // 2.10M
    float* dsumb = ob;                 ob += (size_t)BATCH*NC*DINNER;         // 0.13M
    __hip_bfloat16* bfp = (__hip_bfloat16*)ob;
    __hip_bfloat16* in_w_bf   = bfp;   bfp += (size_t)DEPTH*2*DINNER*DIM;     // 3.15M elem
    __hip_bfloat16* out_w_bf  = bfp;   bfp += (size_t)DEPTH*DIM*DINNER;       // 1.57M
    __hip_bfloat16* ainw_bf   = bfp;   bfp += (size_t)DEPTH*3*DIM*DIM;        // 2.36M
    __hip_bfloat16* aoutw_bf  = bfp;   bfp += (size_t)DEPTH*DIM*DIM;          // 0.79M
    __hip_bfloat16* ybuf_bf   = bfp;   bfp += (size_t)NTOK*DINNER;            // 4.19M
    __hip_bfloat16* abuf_bf   = bfp;   bfp += (size_t)NTOK*DIM;               // 2.10M
    __hip_bfloat16* qbf       = bfp;   bfp += (size_t)NTOK*DIM;               // 2.10M
    __hip_bfloat16* ubf       = bfp;   bfp += (size_t)NTOK*DINNER;            // 4.19M
    __hip_bfloat16* ctx_bf    = bfp;   bfp += (size_t)CTXPAD*DIM;             // 0.26M
    __hip_bfloat16* kv_bf     = bfp;   bfp += (size_t)CTXPAD*KVLD;            // 0.52M
    __hip_bfloat16* xprojw_bf = bfp;   bfp += (size_t)DEPTH*128*DINNER;       // 0.39M
    // total scratch ~23.5M floats < 40.96M (NTOK*VOCAB)

    // ---- weight conversions (once per launch)
    f2bf_kernel<<<(DEPTH*2*DINNER*DIM)/2048, 256, 0, stream>>>(in_w, in_w_bf);
    f2bf_kernel<<<(DEPTH*DIM*DINNER)/2048, 256, 0, stream>>>(out_w, out_w_bf);
    f2bf_kernel<<<(DEPTH*3*DIM*DIM)/2048, 256, 0, stream>>>(ain_w, ainw_bf);
    f2bf_kernel<<<(DEPTH*DIM*DIM)/2048, 256, 0, stream>>>(aout_w, aoutw_bf);
    f2bf_kernel<<<(VOCAB*DIM)/2048, 256, 0, stream>>>(logit_w, logit_w_bf);
    hipMemsetAsync(logit_w_bf + (size_t)VOCAB*DIM, 0,
                   (size_t)(NPAD-VOCAB)*DIM*sizeof(__hip_bfloat16), stream);
    // context -> bf16, pad rows 392..511 with zeros
    f2bf_kernel<<<(BATCH*CTX*DIM)/2048, 256, 0, stream>>>(context, ctx_bf);
    hipMemsetAsync(ctx_bf + (size_t)BATCH*CTX*DIM, 0,
                   (size_t)(CTXPAD - BATCH*CTX)*DIM*sizeof(__hip_bfloat16), stream);
    // xproj_w -> bf16, N padded 64 -> 128 with zeros
    hipMemsetAsync(xprojw_bf, 0, (size_t)DEPTH*128*DINNER*sizeof(__hip_bfloat16), stream);
    for (int i = 0; i < DEPTH; ++i)
        f2bf_kernel<<<(64*DINNER)/2048, 256, 0, stream>>>(
            xproj_w + (size_t)i*64*DINNER, xprojw_bf + (size_t)i*128*DINNER);

    embed_kernel<<<NTOK, 128, 0, stream>>>(x, tok_emb, pos_emb, hbuf);

    float* attn_out_base = out + (size_t)NTOK*VOCAB;

    for (int i = 0; i < DEPTH; ++i){
        const float* Ai = A_log + (size_t)i*DINNER*DSTATE;
        layernorm_kernel<<<NTOK, 256, 0, stream>>>(hbuf, ln1_g + i*DIM, ln1_b + i*DIM, tnorm_bf);
        // in_proj: [4096,512]@[2048,512]^T -> xz (fp32)
        gemm_bf16<0,0,0,0><<<dim3(2*DINNER/128, NTOK/128), 256, 0, stream>>>(
            tnorm_bf, DIM, in_w_bf + (size_t)i*2*DINNER*DIM, DIM, nullptr,
            xz, 2*DINNER, 2*DINNER, DIM);
        conv_silu_kernel<<<(NTOK*DINNER)/256, 256, 0, stream>>>(
            xz, conv_w + (size_t)i*DINNER*DCONV, conv_b + i*DINNER, ubuf, ubf);
        // x_proj (MFMA, N padded to 128, store-masked to 64)
        gemm_bf16<0,0,1,0><<<dim3(1, NTOK/128), 256, 0, stream>>>(
            ubf, DINNER, xprojw_bf + (size_t)i*128*DINNER, DINNER, nullptr,
            xdbl, 64, 64, DINNER);
        // dt_proj + softplus (fp32, K=32, exact delta)
        gemm_f32<1,1,0><<<dim3(DINNER/64, NTOK/64), 256, 0, stream>>>(
            xdbl, 64, dt_w + (size_t)i*DINNER*DTRANK, DTRANK, dt_b + i*DINNER,
            dbuf, DINNER, NTOK, DINNER, DTRANK);
        // chunked selective scan -> ybuf_bf
        scan_pass1<<<dim3(NC, BATCH*4), 256, 0, stream>>>(
            dbuf, ubuf, xdbl, Ai, hend, dsumb);
        scan_pass2<<<(BATCH*DINNER*DSTATE)/256, 256, 0, stream>>>(
            hend, dsumb, Ai, hinb);
        scan_pass3<<<dim3(NC, BATCH*4), 256, 0, stream>>>(
            dbuf, ubuf, xdbl, xz, Ai, D_skip + i*DINNER, hinb, ybuf_bf);
        // out_proj + residual
        gemm_bf16<0,1,0,0><<<dim3(DIM/128, NTOK/128), 256, 0, stream>>>(
            ybuf_bf, DINNER, out_w_bf + (size_t)i*DIM*DINNER, DINNER, nullptr,
            hbuf, DIM, DIM, DINNER);
        layernorm_kernel<<<NTOK, 256, 0, stream>>>(hbuf, ln2_g + i*DIM, ln2_b + i*DIM, tnorm_bf);
        // q proj -> bf16 directly
        gemm_bf16<1,0,0,1><<<dim3(DIM/128, NTOK/128), 256, 0, stream>>>(
            tnorm_bf, DIM, ainw_bf + (size_t)i*3*DIM*DIM, DIM, ain_b + (size_t)i*3*DIM,
            qbf, DIM, DIM, DIM);
        // fused K|V proj (MFMA, M padded 392->512, bf16 out)
        gemm_bf16<1,0,0,1><<<dim3(KVLD/128, CTXPAD/128), 256, 0, stream>>>(
            ctx_bf, DIM, ainw_bf + (size_t)i*3*DIM*DIM + (size_t)DIM*DIM, DIM,
            ain_b + (size_t)i*3*DIM + DIM, kv_bf, KVLD, KVLD, DIM);
        // MFMA attention + head-mean
        attn_mfma_kernel<<<dim3(BATCH*HEADS, SEQ/128), 512, 0, stream>>>(
            qbf, kv_bf, abuf_bf, Pgbuf);
        attn_mean_kernel<<<(NTOK*CTX)/256, 256, 0, stream>>>(
            Pgbuf, attn_out_base + (size_t)i*NTOK*CTX);
        // attn out proj + residual
        gemm_bf16<1,1,0,0><<<dim3(DIM/128, NTOK/128), 256, 0, stream>>>(
            abuf_bf, DIM, aoutw_bf + (size_t)i*DIM*DIM, DIM, aout_b + i*DIM,
            hbuf, DIM, DIM, DIM);
    }
    layernorm_kernel<<<NTOK, 256, 0, stream>>>(hbuf, lnf_g, lnf_b, tnorm_bf);
    // logits: N padded to 10240, store-masked to 10000
    gemm_bf16<1,0,1,0><<<dim3(NPAD/128, NTOK/128), 256, 0, stream>>>(
        tnorm_bf, DIM, logit_w_bf, DIM, logit_b, out, VOCAB, VOCAB, DIM);
}

// Round 3
// 1051.473 us; speedup vs baseline: 1.6595x; 1.0758x over previous
//
#include <hip/hip_runtime.h>
#include <hip/hip_bf16.h>
#include <math.h>

#define DIM 512
#define VOCAB 10000
#define NPAD 10240
#define DEPTH 3
#define DSTATE 16
#define DCONV 4
#define DINNER 1024
#define DTRANK 32
#define BATCH 4
#define SEQ 1024
#define CTX 98
#define HEADS 8
#define DH 64
#define NTOK (BATCH*SEQ)   // 4096
#define NC 32              // scan chunks
#define LC 32              // chunk length
#define KVLD 1024          // fused K|V row stride (bf16 elements)
#define CTXPAD 512         // context rows padded 392 -> 512
#define XKS 4              // x_proj K-split factor

typedef __attribute__((ext_vector_type(8))) short short8;
typedef __attribute__((ext_vector_type(4))) float f32x4;

__device__ __forceinline__ float sigmoidf_(float x){ return 1.f/(1.f+__expf(-x)); }

__device__ __forceinline__ void gload_lds16(const void* g, void* s){
    __builtin_amdgcn_global_load_lds(
        (const __attribute__((address_space(1))) void*)g,
        (__attribute__((address_space(3))) void*)s, 16, 0, 0);
}

__device__ __forceinline__ void cvt8(const float* __restrict__ s, __hip_bfloat16* __restrict__ d){
    float4 a = *(const float4*)s;
    float4 b = *(const float4*)(s+4);
    union { __hip_bfloat16 v[8]; short8 x; } o;
    o.v[0]=__float2bfloat16(a.x); o.v[1]=__float2bfloat16(a.y);
    o.v[2]=__float2bfloat16(a.z); o.v[3]=__float2bfloat16(a.w);
    o.v[4]=__float2bfloat16(b.x); o.v[5]=__float2bfloat16(b.y);
    o.v[6]=__float2bfloat16(b.z); o.v[7]=__float2bfloat16(b.w);
    *(short8*)d = o.x;
}
__device__ __forceinline__ void zero8(__hip_bfloat16* __restrict__ d){
    *(short8*)d = (short8){0,0,0,0,0,0,0,0};
}

// ---------------------------------------------------------------- one-shot weight prep
// converts all fp32 weights to bf16 (with padding) in a single kernel.
#define N_INW   (DEPTH*2*DINNER*DIM)   // 3145728
#define N_OUTW  (DEPTH*DIM*DINNER)     // 1572864
#define N_AINW  (DEPTH*3*DIM*DIM)      // 2359296
#define N_AOUTW (DEPTH*DIM*DIM)        // 786432
#define N_LOGIT (NPAD*DIM)             // 5242880 (valid < VOCAB*DIM)
#define N_CTX   (CTXPAD*DIM)           // 262144 (valid < BATCH*CTX*DIM)
#define N_XPROJ (DEPTH*128*DINNER)     // 393216 (per layer, rows>=64 zero)
#define N_PREP_TOTAL (N_INW+N_OUTW+N_AINW+N_AOUTW+N_LOGIT+N_CTX+N_XPROJ) // 13762560

__global__ __launch_bounds__(256)
void prep_kernel(const float* __restrict__ in_w,   __hip_bfloat16* __restrict__ in_w_bf,
                 const float* __restrict__ out_w,  __hip_bfloat16* __restrict__ out_w_bf,
                 const float* __restrict__ ain_w,  __hip_bfloat16* __restrict__ ainw_bf,
                 const float* __restrict__ aout_w, __hip_bfloat16* __restrict__ aoutw_bf,
                 const float* __restrict__ logit_w,__hip_bfloat16* __restrict__ logit_w_bf,
                 const float* __restrict__ context,__hip_bfloat16* __restrict__ ctx_bf,
                 const float* __restrict__ xproj_w,__hip_bfloat16* __restrict__ xprojw_bf)
{
    int i = (blockIdx.x*256 + threadIdx.x)*8;
    if (i < N_INW){ cvt8(in_w + i, in_w_bf + i); return; }
    i -= N_INW;
    if (i < N_OUTW){ cvt8(out_w + i, out_w_bf + i); return; }
    i -= N_OUTW;
    if (i < N_AINW){ cvt8(ain_w + i, ainw_bf + i); return; }
    i -= N_AINW;
    if (i < N_AOUTW){ cvt8(aout_w + i, aoutw_bf + i); return; }
    i -= N_AOUTW;
    if (i < N_LOGIT){
        if (i < VOCAB*DIM) cvt8(logit_w + i, logit_w_bf + i);
        else zero8(logit_w_bf + i);
        return;
    }
    i -= N_LOGIT;
    if (i < N_CTX){
        if (i < BATCH*CTX*DIM) cvt8(context + i, ctx_bf + i);
        else zero8(ctx_bf + i);
        return;
    }
    i -= N_CTX;
    {   // xproj: dst [3][128][1024], src [3][64][1024], rows >= 64 zero
        int layer = i >> 17;            // / 131072
        int rem   = i & 131071;
        int inrow = rem >> 10;
        if (inrow < 64) cvt8(xproj_w + (layer<<16) + rem, xprojw_bf + i);
        else            zero8(xprojw_bf + i);
    }
}

// ---------------------------------------------------------------- embedding
__global__ __launch_bounds__(128)
void embed_kernel(const int* __restrict__ x,
                  const float* __restrict__ tok_emb,
                  const float* __restrict__ pos_emb,
                  float* __restrict__ h)
{
    int row = blockIdx.x;
    int l = row & (SEQ-1);
    int tok = x[row];
    const float4* te = (const float4*)(tok_emb + (size_t)tok*DIM);
    const float4* pe = (const float4*)(pos_emb + (size_t)l*DIM);
    float4* hp = (float4*)(h + (size_t)row*DIM);
    int i = threadIdx.x;
    float4 a = te[i], b = pe[i];
    hp[i] = make_float4(a.x+b.x, a.y+b.y, a.z+b.z, a.w+b.w);
}

// ---------------------------------------------------------------- layernorm (bf16 out)
__global__ __launch_bounds__(256)
void layernorm_kernel(const float* __restrict__ in, const float* __restrict__ g,
                      const float* __restrict__ b, __hip_bfloat16* __restrict__ out)
{
    int row = blockIdx.x;
    const float* xr = in + (size_t)row*DIM;
    int t = threadIdx.x;
    float2 v = *(const float2*)(xr + t*2);
    float s  = v.x + v.y;
    float s2 = v.x*v.x + v.y*v.y;
    #pragma unroll
    for (int o=32;o>=1;o>>=1){ s += __shfl_xor(s,o); s2 += __shfl_xor(s2,o); }
    __shared__ float ss[4], ss2[4];
    int w = t>>6;
    if ((t&63)==0){ ss[w]=s; ss2[w]=s2; }
    __syncthreads();
    s  = ss[0]+ss[1]+ss[2]+ss[3];
    s2 = ss2[0]+ss2[1]+ss2[2]+ss2[3];
    float mu  = s * (1.f/DIM);
    float var = s2 * (1.f/DIM) - mu*mu;
    float rstd = rsqrtf(var + 1e-5f);
    float2 gg = *(const float2*)(g + t*2);
    float2 bb = *(const float2*)(b + t*2);
    __hip_bfloat162 o2;
    o2.x = __float2bfloat16((v.x-mu)*rstd*gg.x + bb.x);
    o2.y = __float2bfloat16((v.y-mu)*rstd*gg.y + bb.y);
    *(__hip_bfloat162*)(out + (size_t)row*DIM + t*2) = o2;
}

// ---------------------------------------------------------------- bf16 MFMA GEMM
// C[M,N] = A[M,K](bf16) @ W[N,K](bf16)^T (+bias) (+C). 128x128 tile, BK=32,
// 256 thr = 4 waves, each wave 64x64 via 4x4 grid of 16x16x32 MFMAs.
// blockIdx.z batching: A += z*az, W += z*wz, C += z*cz, bias += z*bz.
// (used for 3-layer-batched KV proj and for K-split partial GEMMs)
template<int BIAS, int RES, int NCHECK, int OUTBF>
__global__ __launch_bounds__(256)
void gemm_bf16(const __hip_bfloat16* __restrict__ A, int lda,
               const __hip_bfloat16* __restrict__ W, int ldw,
               const float* __restrict__ bias,
               void* __restrict__ Cv, int ldc, int Nstore, int K,
               size_t az, size_t wz, size_t cz, size_t bz)
{
    __shared__ __hip_bfloat16 As[128*32];
    __shared__ __hip_bfloat16 Ws[128*32];
    int t = threadIdx.x;
    int z = blockIdx.z;
    const __hip_bfloat16* Ap = A + (size_t)z*az;
    const __hip_bfloat16* Wp = W + (size_t)z*wz;
    size_t coff = (size_t)z*cz;
    int w = t >> 6, l = t & 63;
    int m0 = blockIdx.y*128, n0 = blockIdx.x*128;
    int wm = (w>>1)*64, wn = (w&1)*64;
    int lrow = l & 15, lq = l >> 4;
    f32x4 acc[4][4];
    #pragma unroll
    for (int i=0;i<4;i++)
        #pragma unroll
        for (int j=0;j<4;j++)
            acc[i][j] = (f32x4){0.f,0.f,0.f,0.f};

    for (int k0 = 0; k0 < K; k0 += 32){
        __syncthreads();
        #pragma unroll
        for (int it = 0; it < 2; ++it){
            int p = it*256 + t;            // 16B chunk index, 512 chunks/tile
            int r = p >> 2, c = (p & 3)*8;
            gload_lds16(Ap + (size_t)(m0+r)*lda + k0 + c, As + p*8);
            gload_lds16(Wp + (size_t)(n0+r)*ldw + k0 + c, Ws + p*8);
        }
        __syncthreads();
        short8 a[4], b[4];
        #pragma unroll
        for (int mt=0;mt<4;mt++)
            a[mt] = *(const short8*)(As + (wm + mt*16 + lrow)*32 + lq*8);
        #pragma unroll
        for (int nt=0;nt<4;nt++)
            b[nt] = *(const short8*)(Ws + (wn + nt*16 + lrow)*32 + lq*8);
        #pragma unroll
        for (int mt=0;mt<4;mt++)
            #pragma unroll
            for (int nt=0;nt<4;nt++)
                acc[mt][nt] = __builtin_amdgcn_mfma_f32_16x16x32_bf16(
                    a[mt], b[nt], acc[mt][nt], 0, 0, 0);
    }
    // epilogue: D row = wm+mt*16+lq*4+r, col = wn+nt*16+lrow
    #pragma unroll
    for (int nt=0;nt<4;nt++){
        int col = n0 + wn + nt*16 + lrow;
        if (NCHECK && col >= Nstore) continue;
        float bv = BIAS ? bias[(size_t)z*bz + col] : 0.f;
        #pragma unroll
        for (int mt=0;mt<4;mt++){
            #pragma unroll
            for (int r=0;r<4;r++){
                int row = m0 + wm + mt*16 + lq*4 + r;
                float v = acc[mt][nt][r] + bv;
                if (OUTBF){
                    __hip_bfloat16* cp = (__hip_bfloat16*)Cv + coff + (size_t)row*ldc + col;
                    *cp = __float2bfloat16(v);
                } else {
                    float* cp = (float*)Cv + coff + (size_t)row*ldc + col;
                    if (RES) v += *cp;
                    *cp = v;
                }
            }
        }
    }
}

// ---------------------------------------------------------------- reduce x_proj K-split partials
__global__ __launch_bounds__(256)
void xreduce_kernel(const float* __restrict__ p, float* __restrict__ o)
{
    int i = (blockIdx.x*256 + threadIdx.x)*4;
    const size_t S = (size_t)NTOK*64;
    float4 a = *(const float4*)(p+i);
    float4 b = *(const float4*)(p+i+S);
    float4 c = *(const float4*)(p+i+2*S);
    float4 d = *(const float4*)(p+i+3*S);
    *(float4*)(o+i) = make_float4(a.x+b.x+c.x+d.x, a.y+b.y+c.y+d.y,
                                  a.z+b.z+c.z+d.z, a.w+b.w+c.w+d.w);
}

// ---------------------------------------------------------------- generic fp32 GEMM (dt_proj)
template<int ACT, int BIAS, int RES>
__global__ __launch_bounds__(256)
void gemm_f32(const float* __restrict__ A, int lda,
              const float* __restrict__ W, int ldw,
              const float* __restrict__ bias,
              float* __restrict__ C, int ldc,
              int M, int N, int K)
{
    __shared__ float As[16][64];
    __shared__ float Ws[16][64];
    int t = threadIdx.x;
    int tx = t & 15, ty = t >> 4;
    int m0 = blockIdx.y * 64, n0 = blockIdx.x * 64;
    int loadRow = t >> 2;
    int loadK   = (t & 3) << 2;
    float acc[4][4] = {};
    for (int k0 = 0; k0 < K; k0 += 16) {
        {
            int gr = m0 + loadRow;
            float4 a4 = make_float4(0.f,0.f,0.f,0.f);
            if (gr < M) a4 = *(const float4*)(A + (size_t)gr*lda + k0 + loadK);
            As[loadK+0][loadRow] = a4.x;
            As[loadK+1][loadRow] = a4.y;
            As[loadK+2][loadRow] = a4.z;
            As[loadK+3][loadRow] = a4.w;
            int gn = n0 + loadRow;
            float4 w4 = make_float4(0.f,0.f,0.f,0.f);
            if (gn < N) w4 = *(const float4*)(W + (size_t)gn*ldw + k0 + loadK);
            Ws[loadK+0][loadRow] = w4.x;
            Ws[loadK+1][loadRow] = w4.y;
            Ws[loadK+2][loadRow] = w4.z;
            Ws[loadK+3][loadRow] = w4.w;
        }
        __syncthreads();
        #pragma unroll
        for (int k = 0; k < 16; ++k) {
            float4 a4 = *(const float4*)&As[k][ty<<2];
            float4 w4 = *(const float4*)&Ws[k][tx<<2];
            float a[4] = {a4.x,a4.y,a4.z,a4.w};
            float w[4] = {w4.x,w4.y,w4.z,w4.w};
            #pragma unroll
            for (int i=0;i<4;i++)
                #pragma unroll
                for (int j=0;j<4;j++)
                    acc[i][j] = fmaf(a[i], w[j], acc[i][j]);
        }
        __syncthreads();
    }
    #pragma unroll
    for (int i=0;i<4;i++){
        int row = m0 + (ty<<2) + i;
        if (row >= M) continue;
        #pragma unroll
        for (int j=0;j<4;j++){
            int col = n0 + (tx<<2) + j;
            if (col >= N) continue;
            float v = acc[i][j];
            if (BIAS) v += bias[col];
            if (ACT==1) v = (v > 20.f) ? v : log1pf(__expf(v));
            float* cp = C + (size_t)row*ldc + col;
            if (RES) v += *cp;
            *cp = v;
        }
    }
}

// ---------------------------------------------------------------- causal depthwise conv + SiLU (fp32 + bf16 out)
__global__ __launch_bounds__(256)
void conv_silu_kernel(const float* __restrict__ xz, const float* __restrict__ cw,
                      const float* __restrict__ cb, float* __restrict__ u,
                      __hip_bfloat16* __restrict__ ubf)
{
    int idx = blockIdx.x*256 + threadIdx.x;
    int d = idx & (DINNER-1);
    int row = idx >> 10;
    int l = row & (SEQ-1);
    int bbase = row - l;
    float acc = cb[d];
    #pragma unroll
    for (int k=0;k<DCONV;k++){
        int ls = l - (DCONV-1) + k;
        if (ls >= 0)
            acc = fmaf(xz[((size_t)(bbase+ls))*(2*DINNER) + d], cw[d*DCONV+k], acc);
    }
    float uv = acc * sigmoidf_(acc);
    u[idx] = uv;
    ubf[idx] = __float2bfloat16(uv);
}

// ---------------------------------------------------------------- chunked selective scan
__global__ __launch_bounds__(256)
void scan_pass1(const float* __restrict__ delta, const float* __restrict__ u,
                const float* __restrict__ xdbl, const float* __restrict__ A_log,
                float* __restrict__ hend, float* __restrict__ dsum_out)
{
    __shared__ float bc[LC][32];
    int c = blockIdx.x;
    int b = blockIdx.y >> 2, dg = blockIdx.y & 3;
    int t = threadIdx.x;
    int d = dg*256 + t;
    int rowbase = b*SEQ + c*LC;
    for (int idx = t; idx < LC*32; idx += 256){
        int r = idx >> 5, j = idx & 31;
        bc[r][j] = xdbl[(size_t)(rowbase + r)*64 + DTRANK + j];
    }
    float Av[DSTATE];
    #pragma unroll
    for (int s4 = 0; s4 < 4; ++s4){
        float4 a4 = *(const float4*)(A_log + (size_t)d*DSTATE + s4*4);
        Av[s4*4+0] = -__expf(a4.x);
        Av[s4*4+1] = -__expf(a4.y);
        Av[s4*4+2] = -__expf(a4.z);
        Av[s4*4+3] = -__expf(a4.w);
    }
    __syncthreads();
    float h[DSTATE] = {};
    float ds = 0.f;
    for (int tt = 0; tt < LC; ++tt){
        size_t row = (size_t)(rowbase + tt);
        float dlt = delta[row*DINNER + d];
        float uv  = u[row*DINNER + d];
        ds += dlt;
        float du = dlt*uv;
        #pragma unroll
        for (int s = 0; s < DSTATE; ++s)
            h[s] = fmaf(__expf(dlt*Av[s]), h[s], du*bc[tt][s]);
    }
    size_t base = ((size_t)(b*NC + c)*DINNER + d)*DSTATE;
    #pragma unroll
    for (int s4=0;s4<4;s4++)
        *(float4*)(hend + base + s4*4) =
            make_float4(h[s4*4],h[s4*4+1],h[s4*4+2],h[s4*4+3]);
    dsum_out[(size_t)(b*NC+c)*DINNER + d] = ds;
}

__global__ __launch_bounds__(256)
void scan_pass2(const float* __restrict__ hend, const float* __restrict__ dsum,
                const float* __restrict__ A_log, float* __restrict__ hin)
{
    int gid = blockIdx.x*256 + threadIdx.x;
    int s = gid & 15;
    int bd = gid >> 4;
    int d = bd & (DINNER-1);
    int b = bd >> 10;
    float Av = -__expf(A_log[(size_t)d*DSTATE + s]);
    float h = 0.f;
    for (int c = 0; c < NC; ++c){
        size_t idx = ((size_t)(b*NC + c)*DINNER + d)*DSTATE + s;
        hin[idx] = h;
        h = fmaf(__expf(Av*dsum[(size_t)(b*NC+c)*DINNER + d]), h, hend[idx]);
    }
}

// pass3: seeded local scan + y = sum_s h*C, + u*D, * silu(z)  -> bf16 y
__global__ __launch_bounds__(256)
void scan_pass3(const float* __restrict__ delta, const float* __restrict__ u,
                const float* __restrict__ xdbl, const float* __restrict__ xz,
                const float* __restrict__ A_log, const float* __restrict__ D_skip,
                const float* __restrict__ hin, __hip_bfloat16* __restrict__ y)
{
    __shared__ float bc[LC][32];
    int c = blockIdx.x;
    int b = blockIdx.y >> 2, dg = blockIdx.y & 3;
    int t = threadIdx.x;
    int d = dg*256 + t;
    int rowbase = b*SEQ + c*LC;
    for (int idx = t; idx < LC*32; idx += 256){
        int r = idx >> 5, j = idx & 31;
        bc[r][j] = xdbl[(size_t)(rowbase + r)*64 + DTRANK + j];
    }
    float Av[DSTATE];
    #pragma unroll
    for (int s4 = 0; s4 < 4; ++s4){
        float4 a4 = *(const float4*)(A_log + (size_t)d*DSTATE + s4*4);
        Av[s4*4+0] = -__expf(a4.x);
        Av[s4*4+1] = -__expf(a4.y);
        Av[s4*4+2] = -__expf(a4.z);
        Av[s4*4+3] = -__expf(a4.w);
    }
    float h[DSTATE];
    size_t hbase = ((size_t)(b*NC + c)*DINNER + d)*DSTATE;
    #pragma unroll
    for (int s4=0;s4<4;s4++){
        float4 h4 = *(const float4*)(hin + hbase + s4*4);
        h[s4*4+0]=h4.x; h[s4*4+1]=h4.y; h[s4*4+2]=h4.z; h[s4*4+3]=h4.w;
    }
    float Dv = D_skip[d];
    __syncthreads();
    for (int tt = 0; tt < LC; ++tt){
        size_t row = (size_t)(rowbase + tt);
        float dlt = delta[row*DINNER + d];
        float uv  = u[row*DINNER + d];
        float du = dlt*uv;
        float yv = 0.f;
        #pragma unroll
        for (int s = 0; s < DSTATE; ++s){
            h[s] = fmaf(__expf(dlt*Av[s]), h[s], du*bc[tt][s]);
            yv = fmaf(h[s], bc[tt][16+s], yv);
        }
        float zv = xz[row*(2*DINNER) + DINNER + d];
        y[row*DINNER + d] = __float2bfloat16((yv + uv*Dv) * (zv * sigmoidf_(zv)));
    }
}

// ---------------------------------------------------------------- MFMA cross-attention
// grid (B*HEADS, SEQ/128), 512 thr = 8 waves. Per block: one (b,h), 128 q-rows.
// Inputs already bf16: q [NTOK][512], kv [CTXPAD][1024] (K = cols 0..511, V = 512..1023).
// LDS (all bf16, XOR-swizzled rows to kill ds_read_b128 bank conflicts):
//   Qs  [128][64]  q tile (A-operand layout [M][K])
//   Ks  [112][64]  k tile, rows 98..111 zero (B-operand layout [N][K])
//   Vt  [64][128]  V^T (B-operand [N=dh][K=s]), cols 98..127 zero
//   Pt  [128][128] softmax probs (A-operand [M][K]), cols 98..127 zero
#define QS_OFF 0           // 128 * 128B = 16384
#define KS_OFF 16384       // 112 * 128B = 14336
#define VT_OFF 30720       //  64 * 256B = 16384
#define PT_OFF 47104       // 128 * 256B = 32768
#define SMEM_BYTES 79872

__device__ __forceinline__ int swz(int row, int byteoff){
    return byteoff ^ ((row & 7) << 4);
}

__global__ __launch_bounds__(512)
void attn_mfma_kernel(const __hip_bfloat16* __restrict__ q,
                      const __hip_bfloat16* __restrict__ kv,
                      __hip_bfloat16* __restrict__ outp,
                      float* __restrict__ Pg)
{
    __shared__ alignas(16) char smem[SMEM_BYTES];
    int t = threadIdx.x;
    int bh = blockIdx.x;
    int b = bh >> 3, h = bh & 7;
    int lrow0 = blockIdx.y * 128;               // row within batch
    size_t grow0 = (size_t)b*SEQ + lrow0;       // global token row

    // phase A: zero Vt + Pt (padding columns must be 0 for the PV K=128 MFMA)
    #pragma unroll
    for (int it = 0; it < 6; ++it)
        *(f32x4*)(smem + VT_OFF + (it*512 + t)*16) = (f32x4){0.f,0.f,0.f,0.f};
    __syncthreads();

    // phase B: stage Q, K, V^T (bf16 copies, row-XOR swizzle)
    const __hip_bfloat16* qb = q + grow0*DIM + h*DH;
    #pragma unroll
    for (int it = 0; it < 2; ++it){
        int cidx = it*512 + t;                  // 1024 = 128 rows x 8 chunks(16B)
        int row = cidx >> 3, c8 = cidx & 7;
        short8 a = *(const short8*)(qb + (size_t)row*DIM + c8*8);
        *(short8*)(smem + QS_OFF + row*128 + swz(row, c8*16)) = a;
    }
    const __hip_bfloat16* kb = kv + (size_t)(b*CTX)*KVLD + h*DH;
    #pragma unroll
    for (int it = 0; it < 2; ++it){
        int cidx = it*512 + t;                  // need 896 = 112 rows x 8
        if (cidx < 112*8){
            int row = cidx >> 3, c8 = cidx & 7;
            short8 a = (short8){0,0,0,0,0,0,0,0};
            if (row < CTX) a = *(const short8*)(kb + (size_t)row*KVLD + c8*8);
            *(short8*)(smem + KS_OFF + row*128 + swz(row, c8*16)) = a;
        }
    }
    const __hip_bfloat16* vb = kv + (size_t)(b*CTX)*KVLD + DIM + h*DH;
    #pragma unroll
    for (int it = 0; it < 4; ++it){
        int c = it*512 + t;                     // need 1600 = 64 d x 25 s4
        if (c < 1600){
            int d = c & 63, s4 = c >> 6;
            union { unsigned short hh[4]; unsigned long long u; } pk;
            #pragma unroll
            for (int j = 0; j < 4; ++j){
                int s = s4*4 + j;
                pk.hh[j] = (s < CTX) ? *(const unsigned short*)(vb + (size_t)s*KVLD + d) : 0;
            }
            *(unsigned long long*)(smem + VT_OFF + d*256 + swz(d, s4*8)) = pk.u;
        }
    }
    __syncthreads();

    // QK^T: wave w owns rows [w*16, w*16+16); cols 0..111 = 7 n-tiles; K=64
    int w = t >> 6, l = t & 63;
    int lr = l & 15, lq = l >> 4;
    f32x4 acc[7];
    #pragma unroll
    for (int nt = 0; nt < 7; ++nt) acc[nt] = (f32x4){0.f,0.f,0.f,0.f};
    #pragma unroll
    for (int kk = 0; kk < 2; ++kk){
        int arow = w*16 + lr;
        short8 af = *(const short8*)(smem + QS_OFF + arow*128 + swz(arow, kk*64 + lq*16));
        #pragma unroll
        for (int nt = 0; nt < 7; ++nt){
            int brow = nt*16 + lr;
            short8 bf = *(const short8*)(smem + KS_OFF + brow*128 + swz(brow, kk*64 + lq*16));
            acc[nt] = __builtin_amdgcn_mfma_f32_16x16x32_bf16(af, bf, acc[nt], 0, 0, 0);
        }
    }

    // softmax: row = w*16 + lq*4 + r, cols nt*16+lr spread over the 16 lanes
    // sharing lq (consecutive lanes) -> shfl_xor {1,2,4,8}. cols>=98 masked.
    float* Pgp = Pg + ((size_t)bh*SEQ + lrow0)*CTX;
    #pragma unroll
    for (int r = 0; r < 4; ++r){
        int row = w*16 + lq*4 + r;
        float vals[7];
        #pragma unroll
        for (int nt = 0; nt < 7; ++nt) vals[nt] = acc[nt][r] * 0.125f;
        if (lr >= 2) vals[6] = -1e30f;          // cols 98..111 invalid
        float m = vals[0];
        #pragma unroll
        for (int nt = 1; nt < 7; ++nt) m = fmaxf(m, vals[nt]);
        #pragma unroll
        for (int o = 8; o >= 1; o >>= 1) m = fmaxf(m, __shfl_xor(m, o));
        float ssum = 0.f;
        #pragma unroll
        for (int nt = 0; nt < 7; ++nt){ vals[nt] = __expf(vals[nt] - m); ssum += vals[nt]; }
        #pragma unroll
        for (int o = 8; o >= 1; o >>= 1) ssum += __shfl_xor(ssum, o);
        float inv = 1.f / ssum;
        #pragma unroll
        for (int nt = 0; nt < 7; ++nt){
            float p = vals[nt] * inv;
            int col = nt*16 + lr;
            *(__hip_bfloat16*)(smem + PT_OFF + row*256 + swz(row, col*2)) = __float2bfloat16(p);
            if (col < CTX) Pgp[(size_t)row*CTX + col] = p;   // fp32 probs for head-mean
        }
    }
    __syncthreads();

    // PV: out[rows w*16..+16][64] = Pt[rows][0..127] @ Vt; K=128 (4 k-steps)
    f32x4 acc2[4];
    #pragma unroll
    for (int nt = 0; nt < 4; ++nt) acc2[nt] = (f32x4){0.f,0.f,0.f,0.f};
    #pragma unroll
    for (int kk = 0; kk < 4; ++kk){
        int arow = w*16 + lr;
        short8 af = *(const short8*)(smem + PT_OFF + arow*256 + swz(arow, kk*64 + lq*16));
        #pragma unroll
        for (int nt = 0; nt < 4; ++nt){
            int brow = nt*16 + lr;
            short8 bf = *(const short8*)(smem + VT_OFF + brow*256 + swz(brow, kk*64 + lq*16));
            acc2[nt] = __builtin_amdgcn_mfma_f32_16x16x32_bf16(af, bf, acc2[nt], 0, 0, 0);
        }
    }
    #pragma unroll
    for (int nt = 0; nt < 4; ++nt){
        int col = h*DH + nt*16 + lr;
        #pragma unroll
        for (int r = 0; r < 4; ++r){
            int row = w*16 + lq*4 + r;
            outp[(grow0 + row)*DIM + col] = __float2bfloat16(acc2[nt][r]);
        }
    }
}

// mean over heads: attn_mean[b,l,s] = (1/8) sum_h Pg[b,h,l,s]
__global__ __launch_bounds__(256)
void attn_mean_kernel(const float* __restrict__ Pg, float* __restrict__ am)
{
    int idx = blockIdx.x*256 + threadIdx.x;     // NTOK*CTX = 401408 exact
    int row = idx / CTX;
    int s = idx - row*CTX;
    int b = row >> 10;
    int l = row & (SEQ-1);
    const float* p = Pg + ((size_t)(b*HEADS)*SEQ + l)*CTX + s;
    float acc = 0.f;
    #pragma unroll
    for (int h = 0; h < HEADS; ++h) acc += p[(size_t)h*SEQ*CTX];
    am[idx] = acc * 0.125f;
}

// ---------------------------------------------------------------- launcher
extern "C" void kernel_launch(void* const* d_in, const int* in_sizes, int n_in,
                              void* d_out, int out_size, void* d_ws, size_t ws_size,
                              hipStream_t stream)
{
    (void)in_sizes; (void)n_in; (void)out_size; (void)ws_size;
    const int*   x        = (const int*)  d_in[0];
    const float* context  = (const float*)d_in[1];
    const float* tok_emb  = (const float*)d_in[2];
    const float* pos_emb  = (const float*)d_in[3];
    const float* ln1_g    = (const float*)d_in[4];
    const float* ln1_b    = (const float*)d_in[5];
    const float* in_w     = (const float*)d_in[6];
    const float* conv_w   = (const float*)d_in[7];
    const float* conv_b   = (const float*)d_in[8];
    const float* xproj_w  = (const float*)d_in[9];
    const float* dt_w     = (const float*)d_in[10];
    const float* dt_b     = (const float*)d_in[11];
    const float* A_log    = (const float*)d_in[12];
    const float* D_skip   = (const float*)d_in[13];
    const float* out_w    = (const float*)d_in[14];
    const float* ln2_g    = (const float*)d_in[15];
    const float* ln2_b    = (const float*)d_in[16];
    const float* ain_w    = (const float*)d_in[17];
    const float* ain_b    = (const float*)d_in[18];
    const float* aout_w   = (const float*)d_in[19];
    const float* aout_b   = (const float*)d_in[20];
    const float* lnf_g    = (const float*)d_in[21];
    const float* lnf_b    = (const float*)d_in[22];
    const float* logit_w  = (const float*)d_in[23];
    const float* logit_b  = (const float*)d_in[24];
    float* out = (float*)d_out;

    // ---- workspace (fp32 + bf16 staging), ~15.5M floats
    float* ws = (float*)d_ws;
    size_t off = 0;
    float* hbuf  = ws + off;  off += (size_t)NTOK*DIM;        // 2.10M
    float* ubuf  = ws + off;  off += (size_t)NTOK*DINNER;     // 4.19M
    float* xdbl  = ws + off;  off += (size_t)NTOK*64;         // 0.26M
    float* dbuf  = ws + off;  off += (size_t)NTOK*DINNER;     // 4.19M
    float* xpart = ws + off;  off += (size_t)XKS*NTOK*64;     // 1.05M
    __hip_bfloat16* tnorm_bf   = (__hip_bfloat16*)(ws + off); off += (size_t)NTOK*DIM/2;
    __hip_bfloat16* logit_w_bf = (__hip_bfloat16*)(ws + off); off += (size_t)NPAD*DIM/2;
    float* Pgbuf = dbuf;                      // dead after scan; 3.21M < 4.19M floats

    // ---- scratch in dead logits region of d_out (first 40.96M floats)
    float* ob = out;
    float* xz    = ob;                 ob += (size_t)NTOK*2*DINNER;           // 8.39M
    float* hend  = ob;                 ob += (size_t)BATCH*NC*DINNER*DSTATE;  // 2.10M
    float* hinb  = ob;                 ob += (size_t)BATCH*NC*DINNER*DSTATE;  // 2.10M
    float* dsumb = ob;                 ob += (size_t)BATCH*NC*DINNER;         // 0.13M
    __hip_bfloat16* bfp = (__hip_bfloat16*)ob;
    __hip_bfloat16* in_w_bf   = bfp;   bfp += (size_t)N_INW;
    __hip_bfloat16* out_w_bf  = bfp;   bfp += (size_t)N_OUTW;
    __hip_bfloat16* ainw_bf   = bfp;   bfp += (size_t)N_AINW;
    __hip_bfloat16* aoutw_bf  = bfp;   bfp += (size_t)N_AOUTW;
    __hip_bfloat16* ybuf_bf   = bfp;   bfp += (size_t)NTOK*DINNER;            // 4.19M
    __hip_bfloat16* abuf_bf   = bfp;   bfp += (size_t)NTOK*DIM;               // 2.10M
    __hip_bfloat16* qbf       = bfp;   bfp += (size_t)NTOK*DIM;               // 2.10M
    __hip_bfloat16* ubf       = bfp;   bfp += (size_t)NTOK*DINNER;            // 4.19M
    __hip_bfloat16* ctx_bf    = bfp;   bfp += (size_t)N_CTX;
    __hip_bfloat16* kv_bf     = bfp;   bfp += (size_t)DEPTH*CTXPAD*KVLD;      // 1.57M
    __hip_bfloat16* xprojw_bf = bfp;   bfp += (size_t)N_XPROJ;
    // total scratch ~24M floats < 40.96M (NTOK*VOCAB)

    // ---- one-shot weight prep (all conversions + padding in one kernel)
    prep_kernel<<<N_PREP_TOTAL/2048, 256, 0, stream>>>(
        in_w, in_w_bf, out_w, out_w_bf, ain_w, ainw_bf, aout_w, aoutw_bf,
        logit_w, logit_w_bf, context, ctx_bf, xproj_w, xprojw_bf);

    embed_kernel<<<NTOK, 128, 0, stream>>>(x, tok_emb, pos_emb, hbuf);

    // ---- batched 3-layer K|V projection (context-only, hoisted out of the loop)
    gemm_bf16<1,0,0,1><<<dim3(KVLD/128, CTXPAD/128, DEPTH), 256, 0, stream>>>(
        ctx_bf, DIM, ainw_bf + (size_t)DIM*DIM, DIM, ain_b + DIM,
        kv_bf, KVLD, KVLD, DIM,
        0, (size_t)3*DIM*DIM, (size_t)CTXPAD*KVLD, (size_t)3*DIM);

    float* attn_out_base = out + (size_t)NTOK*VOCAB;

    for (int i = 0; i < DEPTH; ++i){
        const float* Ai = A_log + (size_t)i*DINNER*DSTATE;
        layernorm_kernel<<<NTOK, 256, 0, stream>>>(hbuf, ln1_g + i*DIM, ln1_b + i*DIM, tnorm_bf);
        // in_proj: [4096,512]@[2048,512]^T -> xz (fp32)
        gemm_bf16<0,0,0,0><<<dim3(2*DINNER/128, NTOK/128), 256, 0, stream>>>(
            tnorm_bf, DIM, in_w_bf + (size_t)i*2*DINNER*DIM, DIM, nullptr,
            xz, 2*DINNER, 2*DINNER, DIM, 0, 0, 0, 0);
        conv_silu_kernel<<<(NTOK*DINNER)/256, 256, 0, stream>>>(
            xz, conv_w + (size_t)i*DINNER*DCONV, conv_b + i*DINNER, ubuf, ubf);
        // x_proj: K-split x4 MFMA partial GEMMs (grid z = k-chunk) + reduce
        gemm_bf16<0,0,1,0><<<dim3(1, NTOK/128, XKS), 256, 0, stream>>>(
            ubf, DINNER, xprojw_bf + (size_t)i*128*DINNER, DINNER, nullptr,
            xpart, 64, 64, DINNER/XKS,
            (size_t)(DINNER/XKS), (size_t)(DINNER/XKS), (size_t)NTOK*64, 0);
        xreduce_kernel<<<(NTOK*64)/1024, 256, 0, stream>>>(xpart, xdbl);
        // dt_proj + softplus (fp32, K=32, exact delta)
        gemm_f32<1,1,0><<<dim3(DINNER/64, NTOK/64), 256, 0, stream>>>(
            xdbl, 64, dt_w + (size_t)i*DINNER*DTRANK, DTRANK, dt_b + i*DINNER,
            dbuf, DINNER, NTOK, DINNER, DTRANK);
        // chunked selective scan -> ybuf_bf
        scan_pass1<<<dim3(NC, BATCH*4), 256, 0, stream>>>(
            dbuf, ubuf, xdbl, Ai, hend, dsumb);
        scan_pass2<<<(BATCH*DINNER*DSTATE)/256, 256, 0, stream>>>(
            hend, dsumb, Ai, hinb);
        scan_pass3<<<dim3(NC, BATCH*4), 256, 0, stream>>>(
            dbuf, ubuf, xdbl, xz, Ai, D_skip + i*DINNER, hinb, ybuf_bf);
        // out_proj + residual
        gemm_bf16<0,1,0,0><<<dim3(DIM/128, NTOK/128), 256, 0, stream>>>(
            ybuf_bf, DINNER, out_w_bf + (size_t)i*DIM*DINNER, DINNER, nullptr,
            hbuf, DIM, DIM, DINNER, 0, 0, 0, 0);
        layernorm_kernel<<<NTOK, 256, 0, stream>>>(hbuf, ln2_g + i*DIM, ln2_b + i*DIM, tnorm_bf);
        // q proj -> bf16 directly
        gemm_bf16<1,0,0,1><<<dim3(DIM/128, NTOK/128), 256, 0, stream>>>(
            tnorm_bf, DIM, ainw_bf + (size_t)i*3*DIM*DIM, DIM, ain_b + (size_t)i*3*DIM,
            qbf, DIM, DIM, DIM, 0, 0, 0, 0);
        // MFMA attention + head-mean
        attn_mfma_kernel<<<dim3(BATCH*HEADS, SEQ/128), 512, 0, stream>>>(
            qbf, kv_bf + (size_t)i*CTXPAD*KVLD, abuf_bf, Pgbuf);
        attn_mean_kernel<<<(NTOK*CTX)/256, 256, 0, stream>>>(
            Pgbuf, attn_out_base + (size_t)i*NTOK*CTX);
        // attn out proj + residual
        gemm_bf16<1,1,0,0><<<dim3(DIM/128, NTOK/128), 256, 0, stream>>>(
            abuf_bf, DIM, aoutw_bf + (size_t)i*DIM*DIM, DIM, aout_b + i*DIM,
            hbuf, DIM, DIM, DIM, 0, 0, 0, 0);
    }
    layernorm_kernel<<<NTOK, 256, 0, stream>>>(hbuf, lnf_g, lnf_b, tnorm_bf);
    // logits: N padded to 10240, store-masked to 10000
    gemm_bf16<1,0,1,0><<<dim3(NPAD/128, NTOK/128), 256, 0, stream>>>(
        tnorm_bf, DIM, logit_w_bf, DIM, logit_b, out, VOCAB, VOCAB, DIM, 0, 0, 0, 0);
}